// Round 1
// baseline (1613.824 us; speedup 1.0000x reference)
//
#include <hip/hip_runtime.h>

#define NN 100000
#define NE 3200000

// ---------- helpers ----------
__device__ __forceinline__ float4 f4fma(float s, float4 a, float4 c) {
  c.x = fmaf(s, a.x, c.x); c.y = fmaf(s, a.y, c.y);
  c.z = fmaf(s, a.z, c.z); c.w = fmaf(s, a.w, c.w);
  return c;
}

// quad broadcast via DPP (VALU pipe, not LDS): CTRL = k*0x55 broadcasts quad lane k
template<int CTRL>
__device__ __forceinline__ float4 quad_bcast(float4 v) {
  float4 r;
  r.x = __int_as_float(__builtin_amdgcn_update_dpp(__float_as_int(v.x), __float_as_int(v.x), CTRL, 0xF, 0xF, false));
  r.y = __int_as_float(__builtin_amdgcn_update_dpp(__float_as_int(v.y), __float_as_int(v.y), CTRL, 0xF, 0xF, false));
  r.z = __int_as_float(__builtin_amdgcn_update_dpp(__float_as_int(v.z), __float_as_int(v.z), CTRL, 0xF, 0xF, false));
  r.w = __int_as_float(__builtin_amdgcn_update_dpp(__float_as_int(v.w), __float_as_int(v.w), CTRL, 0xF, 0xF, false));
  return r;
}

// edge_index may be int32 or int64 (values < 2^31, nonneg -> int64 high words are 0)
__device__ __forceinline__ int edge_val(const int* __restrict__ ei, int idx, bool w64) {
  return w64 ? ei[2 * idx] : ei[idx];
}

// ---------- kernels ----------
__global__ void detect_kernel(const int* __restrict__ ei, int* __restrict__ flag) {
  if (threadIdx.x == 0 && blockIdx.x == 0) {
    int o = 0;
    for (int i = 1; i < 64; i += 2) o |= ei[i];
    *flag = (o == 0) ? 1 : 0;   // 1 => int64 layout
  }
}

__global__ __launch_bounds__(256) void deg_kernel(const int* __restrict__ ei,
                                                  int* __restrict__ deg,
                                                  const int* __restrict__ flag) {
  int e = blockIdx.x * 256 + threadIdx.x;
  if (e >= NE) return;
  bool w64 = (*flag != 0);
  int d = edge_val(ei, NE + e, w64);
  atomicAdd(&deg[d], 1);
}

__global__ __launch_bounds__(256) void dinv_kernel(const int* __restrict__ deg,
                                                   float* __restrict__ dinv) {
  int n = blockIdx.x * 256 + threadIdx.x;
  if (n >= NN) return;
  dinv[n] = rsqrtf((float)deg[n] + 1.0f);  // +1 self loop; always > 0
}

// xw1[n][16] = x[n][256] @ W1[256][16]; wave-per-node, W1 in registers.
// lane: cg = lane>>2 (channel group of 16), jl = lane&3 (4 outputs j = jl*4..+3)
__global__ __launch_bounds__(256) void gemm1_kernel(const float* __restrict__ x,
                                                    const float* __restrict__ W1,
                                                    float* __restrict__ xw1) {
  const int lane = threadIdx.x & 63;
  const int wv   = threadIdx.x >> 6;
  const int node = blockIdx.x * 4 + wv;
  const int cg = lane >> 2;
  const int jl = lane & 3;
  float4 w[16];
#pragma unroll
  for (int k = 0; k < 4; ++k)
#pragma unroll
    for (int c = 0; c < 4; ++c)
      w[k * 4 + c] = *(const float4*)(W1 + (cg * 16 + k * 4 + c) * 16 + jl * 4);
  if (node >= NN) return;
  float4 xv = *(const float4*)(x + (size_t)node * 256 + lane * 4);
  float4 acc = make_float4(0.f, 0.f, 0.f, 0.f);
  {
    float4 b = quad_bcast<0x00>(xv);
    acc = f4fma(b.x, w[0], acc);  acc = f4fma(b.y, w[1], acc);
    acc = f4fma(b.z, w[2], acc);  acc = f4fma(b.w, w[3], acc);
  }
  {
    float4 b = quad_bcast<0x55>(xv);
    acc = f4fma(b.x, w[4], acc);  acc = f4fma(b.y, w[5], acc);
    acc = f4fma(b.z, w[6], acc);  acc = f4fma(b.w, w[7], acc);
  }
  {
    float4 b = quad_bcast<0xAA>(xv);
    acc = f4fma(b.x, w[8], acc);  acc = f4fma(b.y, w[9], acc);
    acc = f4fma(b.z, w[10], acc); acc = f4fma(b.w, w[11], acc);
  }
  {
    float4 b = quad_bcast<0xFF>(xv);
    acc = f4fma(b.x, w[12], acc); acc = f4fma(b.y, w[13], acc);
    acc = f4fma(b.z, w[14], acc); acc = f4fma(b.w, w[15], acc);
  }
#pragma unroll
  for (int m = 4; m <= 32; m <<= 1) {
    acc.x += __shfl_xor(acc.x, m);
    acc.y += __shfl_xor(acc.y, m);
    acc.z += __shfl_xor(acc.z, m);
    acc.w += __shfl_xor(acc.w, m);
  }
  if (lane < 4)
    *(float4*)(xw1 + node * 16 + lane * 4) = acc;
}

// 4 threads per edge, each handles 4 features
__global__ __launch_bounds__(256) void agg1_kernel(const int* __restrict__ ei,
                                                   const float* __restrict__ dinv,
                                                   const float* __restrict__ xw1,
                                                   float* __restrict__ agg1,
                                                   const int* __restrict__ flag) {
  int t = blockIdx.x * 256 + threadIdx.x;
  int e = t >> 2, q = t & 3;
  if (e >= NE) return;
  bool w64 = (*flag != 0);
  int s = edge_val(ei, e, w64);
  int d = edge_val(ei, NE + e, w64);
  float wgt = dinv[s] * dinv[d];
  float4 v = *(const float4*)(xw1 + s * 16 + q * 4);
  float* o = agg1 + d * 16 + q * 4;
  atomicAdd(o + 0, v.x * wgt);
  atomicAdd(o + 1, v.y * wgt);
  atomicAdd(o + 2, v.z * wgt);
  atomicAdd(o + 3, v.w * wgt);
}

// self-loop + bias + relu + h1 @ W2 (16x8) fused
__global__ __launch_bounds__(256) void post1_kernel(const float* __restrict__ agg1,
                                                    const float* __restrict__ xw1,
                                                    const float* __restrict__ dinv,
                                                    const float* __restrict__ W2,
                                                    const float* __restrict__ b1,
                                                    float* __restrict__ h1w2) {
  int n = blockIdx.x * 256 + threadIdx.x;
  if (n >= NN) return;
  float di = dinv[n], d2 = di * di;
  float h[16];
#pragma unroll
  for (int g = 0; g < 4; ++g) {
    float4 a  = *(const float4*)(agg1 + n * 16 + g * 4);
    float4 xs = *(const float4*)(xw1 + n * 16 + g * 4);
    h[g * 4 + 0] = fmaxf(fmaf(xs.x, d2, a.x) + b1[g * 4 + 0], 0.f);
    h[g * 4 + 1] = fmaxf(fmaf(xs.y, d2, a.y) + b1[g * 4 + 1], 0.f);
    h[g * 4 + 2] = fmaxf(fmaf(xs.z, d2, a.z) + b1[g * 4 + 2], 0.f);
    h[g * 4 + 3] = fmaxf(fmaf(xs.w, d2, a.w) + b1[g * 4 + 3], 0.f);
  }
  float acc[8] = {0.f, 0.f, 0.f, 0.f, 0.f, 0.f, 0.f, 0.f};
#pragma unroll
  for (int f = 0; f < 16; ++f)
#pragma unroll
    for (int j = 0; j < 8; ++j)
      acc[j] = fmaf(h[f], W2[f * 8 + j], acc[j]);  // uniform addr -> scalar loads
  *(float4*)(h1w2 + n * 8)     = make_float4(acc[0], acc[1], acc[2], acc[3]);
  *(float4*)(h1w2 + n * 8 + 4) = make_float4(acc[4], acc[5], acc[6], acc[7]);
}

// 2 threads per edge, each handles 4 of 8 features
__global__ __launch_bounds__(256) void agg2_kernel(const int* __restrict__ ei,
                                                   const float* __restrict__ dinv,
                                                   const float* __restrict__ h1w2,
                                                   float* __restrict__ agg2,
                                                   const int* __restrict__ flag) {
  int t = blockIdx.x * 256 + threadIdx.x;
  int e = t >> 1, q = t & 1;
  if (e >= NE) return;
  bool w64 = (*flag != 0);
  int s = edge_val(ei, e, w64);
  int d = edge_val(ei, NE + e, w64);
  float wgt = dinv[s] * dinv[d];
  float4 v = *(const float4*)(h1w2 + s * 8 + q * 4);
  float* o = agg2 + d * 8 + q * 4;
  atomicAdd(o + 0, v.x * wgt);
  atomicAdd(o + 1, v.y * wgt);
  atomicAdd(o + 2, v.z * wgt);
  atomicAdd(o + 3, v.w * wgt);
}

// self-loop + bias + log_softmax(8)
__global__ __launch_bounds__(256) void final_kernel(const float* __restrict__ agg2,
                                                    const float* __restrict__ h1w2,
                                                    const float* __restrict__ dinv,
                                                    const float* __restrict__ b2,
                                                    float* __restrict__ out) {
  int n = blockIdx.x * 256 + threadIdx.x;
  if (n >= NN) return;
  float di = dinv[n], d2 = di * di;
  float4 a0 = *(const float4*)(agg2 + n * 8);
  float4 a1 = *(const float4*)(agg2 + n * 8 + 4);
  float4 s0 = *(const float4*)(h1w2 + n * 8);
  float4 s1 = *(const float4*)(h1w2 + n * 8 + 4);
  float v[8];
  v[0] = fmaf(s0.x, d2, a0.x) + b2[0];
  v[1] = fmaf(s0.y, d2, a0.y) + b2[1];
  v[2] = fmaf(s0.z, d2, a0.z) + b2[2];
  v[3] = fmaf(s0.w, d2, a0.w) + b2[3];
  v[4] = fmaf(s1.x, d2, a1.x) + b2[4];
  v[5] = fmaf(s1.y, d2, a1.y) + b2[5];
  v[6] = fmaf(s1.z, d2, a1.z) + b2[6];
  v[7] = fmaf(s1.w, d2, a1.w) + b2[7];
  float m = v[0];
#pragma unroll
  for (int j = 1; j < 8; ++j) m = fmaxf(m, v[j]);
  float sum = 0.f;
#pragma unroll
  for (int j = 0; j < 8; ++j) sum += expf(v[j] - m);
  float ls = m + logf(sum);
  *(float4*)(out + n * 8)     = make_float4(v[0] - ls, v[1] - ls, v[2] - ls, v[3] - ls);
  *(float4*)(out + n * 8 + 4) = make_float4(v[4] - ls, v[5] - ls, v[6] - ls, v[7] - ls);
}

// ---------- launch ----------
extern "C" void kernel_launch(void* const* d_in, const int* in_sizes, int n_in,
                              void* d_out, int out_size, void* d_ws, size_t ws_size,
                              hipStream_t stream) {
  const float* x  = (const float*)d_in[0];
  const int*   ei = (const int*)d_in[1];
  const float* W1 = (const float*)d_in[2];
  const float* b1 = (const float*)d_in[3];
  const float* W2 = (const float*)d_in[4];
  const float* b2 = (const float*)d_in[5];
  float* out = (float*)d_out;

  // ws layout (floats): [agg1 16N][agg2 8N][deg N] <- zeroed; [dinv N][xw1 16N][h1w2 8N][flag]
  float* agg1 = (float*)d_ws;
  float* agg2 = agg1 + (size_t)16 * NN;
  int*   deg  = (int*)(agg2 + (size_t)8 * NN);
  float* dinv = (float*)(deg + NN);
  float* xw1  = dinv + NN;
  float* h1w2 = xw1 + (size_t)16 * NN;
  int*   flag = (int*)(h1w2 + (size_t)8 * NN);

  hipMemsetAsync(d_ws, 0, (size_t)25 * NN * sizeof(float), stream);
  detect_kernel<<<1, 64, 0, stream>>>(ei, flag);
  deg_kernel<<<NE / 256, 256, 0, stream>>>(ei, deg, flag);
  dinv_kernel<<<(NN + 255) / 256, 256, 0, stream>>>(deg, dinv);
  gemm1_kernel<<<NN / 4, 256, 0, stream>>>(x, W1, xw1);
  agg1_kernel<<<(NE * 4) / 256, 256, 0, stream>>>(ei, dinv, xw1, agg1, flag);
  post1_kernel<<<(NN + 255) / 256, 256, 0, stream>>>(agg1, xw1, dinv, W2, b1, h1w2);
  agg2_kernel<<<(NE * 2) / 256, 256, 0, stream>>>(ei, dinv, h1w2, agg2, flag);
  final_kernel<<<(NN + 255) / 256, 256, 0, stream>>>(agg2, h1w2, dinv, b2, out);
}

// Round 2
// 718.834 us; speedup vs baseline: 2.2451x; 2.2451x over previous
//
#include <hip/hip_runtime.h>

#define NN 100000
#define NE 3200000

// ---------- helpers ----------
__device__ __forceinline__ float4 f4fma(float s, float4 a, float4 c) {
  c.x = fmaf(s, a.x, c.x); c.y = fmaf(s, a.y, c.y);
  c.z = fmaf(s, a.z, c.z); c.w = fmaf(s, a.w, c.w);
  return c;
}

template<int CTRL>
__device__ __forceinline__ float4 quad_bcast(float4 v) {
  float4 r;
  r.x = __int_as_float(__builtin_amdgcn_update_dpp(__float_as_int(v.x), __float_as_int(v.x), CTRL, 0xF, 0xF, false));
  r.y = __int_as_float(__builtin_amdgcn_update_dpp(__float_as_int(v.y), __float_as_int(v.y), CTRL, 0xF, 0xF, false));
  r.z = __int_as_float(__builtin_amdgcn_update_dpp(__float_as_int(v.z), __float_as_int(v.z), CTRL, 0xF, 0xF, false));
  r.w = __int_as_float(__builtin_amdgcn_update_dpp(__float_as_int(v.w), __float_as_int(v.w), CTRL, 0xF, 0xF, false));
  return r;
}

// edge_index may be int32 or int64 (values < 2^31, nonneg -> int64 high words are 0)
__device__ __forceinline__ int edge_val(const int* __restrict__ ei, int idx, bool w64) {
  return w64 ? ei[2 * idx] : ei[idx];
}

// ---------- kernels ----------
__global__ void detect_kernel(const int* __restrict__ ei, int* __restrict__ flag) {
  if (threadIdx.x == 0 && blockIdx.x == 0) {
    int o = 0;
    for (int i = 1; i < 64; i += 2) o |= ei[i];
    *flag = (o == 0) ? 1 : 0;   // 1 => int64 layout
  }
}

__global__ __launch_bounds__(256) void deg_kernel(const int* __restrict__ ei,
                                                  int* __restrict__ deg,
                                                  const int* __restrict__ flag) {
  int e = blockIdx.x * 256 + threadIdx.x;
  if (e >= NE) return;
  bool w64 = (*flag != 0);
  int d = edge_val(ei, NE + e, w64);
  atomicAdd(&deg[d], 1);
}

__global__ __launch_bounds__(256) void dinv_kernel(const int* __restrict__ deg,
                                                   float* __restrict__ dinv) {
  int n = blockIdx.x * 256 + threadIdx.x;
  if (n >= NN) return;
  dinv[n] = rsqrtf((float)deg[n] + 1.0f);  // +1 self loop; always > 0
}

// CSR row allocation: block-scan of deg + one global atomic per block.
// Rows are contiguous per 256-node group; node order within group preserved.
__global__ __launch_bounds__(256) void alloc_kernel(const int* __restrict__ deg,
                                                    int* __restrict__ row_ofs,
                                                    int* __restrict__ cursor,
                                                    int* __restrict__ total) {
  __shared__ int sc[256];
  __shared__ int base_s;
  int t = threadIdx.x;
  int n = blockIdx.x * 256 + t;
  int v = (n < NN) ? deg[n] : 0;
  sc[t] = v;
  __syncthreads();
#pragma unroll
  for (int off = 1; off < 256; off <<= 1) {
    int u = (t >= off) ? sc[t - off] : 0;
    __syncthreads();
    sc[t] += u;
    __syncthreads();
  }
  if (t == 255) base_s = atomicAdd(total, sc[255]);
  __syncthreads();
  if (n < NN) {
    int start = base_s + sc[t] - v;
    row_ofs[n] = start;
    cursor[n]  = start;
  }
}

// counting-sort scatter: place src of each edge into its dst row
__global__ __launch_bounds__(256) void scatter_kernel(const int* __restrict__ ei,
                                                      int* __restrict__ cursor,
                                                      int* __restrict__ srt,
                                                      const int* __restrict__ flag) {
  int e = blockIdx.x * 256 + threadIdx.x;
  if (e >= NE) return;
  bool w64 = (*flag != 0);
  int s = edge_val(ei, e, w64);
  int d = edge_val(ei, NE + e, w64);
  int pos = atomicAdd(&cursor[d], 1);
  srt[pos] = s;
}

// xw1[n][16] = x[n][256] @ W1[256][16]; wave-per-node, W1 in registers.
__global__ __launch_bounds__(256) void gemm1_kernel(const float* __restrict__ x,
                                                    const float* __restrict__ W1,
                                                    float* __restrict__ xw1) {
  const int lane = threadIdx.x & 63;
  const int wv   = threadIdx.x >> 6;
  const int node = blockIdx.x * 4 + wv;
  const int cg = lane >> 2;
  const int jl = lane & 3;
  float4 w[16];
#pragma unroll
  for (int k = 0; k < 4; ++k)
#pragma unroll
    for (int c = 0; c < 4; ++c)
      w[k * 4 + c] = *(const float4*)(W1 + (cg * 16 + k * 4 + c) * 16 + jl * 4);
  if (node >= NN) return;
  float4 xv = *(const float4*)(x + (size_t)node * 256 + lane * 4);
  float4 acc = make_float4(0.f, 0.f, 0.f, 0.f);
  {
    float4 b = quad_bcast<0x00>(xv);
    acc = f4fma(b.x, w[0], acc);  acc = f4fma(b.y, w[1], acc);
    acc = f4fma(b.z, w[2], acc);  acc = f4fma(b.w, w[3], acc);
  }
  {
    float4 b = quad_bcast<0x55>(xv);
    acc = f4fma(b.x, w[4], acc);  acc = f4fma(b.y, w[5], acc);
    acc = f4fma(b.z, w[6], acc);  acc = f4fma(b.w, w[7], acc);
  }
  {
    float4 b = quad_bcast<0xAA>(xv);
    acc = f4fma(b.x, w[8], acc);  acc = f4fma(b.y, w[9], acc);
    acc = f4fma(b.z, w[10], acc); acc = f4fma(b.w, w[11], acc);
  }
  {
    float4 b = quad_bcast<0xFF>(xv);
    acc = f4fma(b.x, w[12], acc); acc = f4fma(b.y, w[13], acc);
    acc = f4fma(b.z, w[14], acc); acc = f4fma(b.w, w[15], acc);
  }
#pragma unroll
  for (int m = 4; m <= 32; m <<= 1) {
    acc.x += __shfl_xor(acc.x, m);
    acc.y += __shfl_xor(acc.y, m);
    acc.z += __shfl_xor(acc.z, m);
    acc.w += __shfl_xor(acc.w, m);
  }
  if (lane < 4)
    *(float4*)(xw1 + node * 16 + lane * 4) = acc;
}

// CSR gather layer 1: 4 lanes per node (lane q covers feats 4q..4q+3).
// Quad reads one 64B line of xw1 per edge -> fully coalesced.
// acc = sum_e dinv[s_e] * xw1[s_e]; write dinv[n] * acc.
__global__ __launch_bounds__(256) void gather1_kernel(const int* __restrict__ srt,
                                                      const int* __restrict__ row_ofs,
                                                      const int* __restrict__ deg,
                                                      const float* __restrict__ dinv,
                                                      const float* __restrict__ xw1,
                                                      float* __restrict__ agg1) {
  int t = blockIdx.x * 256 + threadIdx.x;
  int n = t >> 2, q = t & 3;
  if (n >= NN) return;
  int base = row_ofs[n], cnt = deg[n];
  float4 acc = make_float4(0.f, 0.f, 0.f, 0.f);
  for (int i = 0; i < cnt; ++i) {
    int s = srt[base + i];
    float w = dinv[s];
    float4 v = *(const float4*)(xw1 + s * 16 + q * 4);
    acc = f4fma(w, v, acc);
  }
  float dn = dinv[n];
  acc.x *= dn; acc.y *= dn; acc.z *= dn; acc.w *= dn;
  *(float4*)(agg1 + n * 16 + q * 4) = acc;
}

// self-loop + bias + relu + h1 @ W2 (16x8) fused
__global__ __launch_bounds__(256) void post1_kernel(const float* __restrict__ agg1,
                                                    const float* __restrict__ xw1,
                                                    const float* __restrict__ dinv,
                                                    const float* __restrict__ W2,
                                                    const float* __restrict__ b1,
                                                    float* __restrict__ h1w2) {
  int n = blockIdx.x * 256 + threadIdx.x;
  if (n >= NN) return;
  float di = dinv[n], d2 = di * di;
  float h[16];
#pragma unroll
  for (int g = 0; g < 4; ++g) {
    float4 a  = *(const float4*)(agg1 + n * 16 + g * 4);
    float4 xs = *(const float4*)(xw1 + n * 16 + g * 4);
    h[g * 4 + 0] = fmaxf(fmaf(xs.x, d2, a.x) + b1[g * 4 + 0], 0.f);
    h[g * 4 + 1] = fmaxf(fmaf(xs.y, d2, a.y) + b1[g * 4 + 1], 0.f);
    h[g * 4 + 2] = fmaxf(fmaf(xs.z, d2, a.z) + b1[g * 4 + 2], 0.f);
    h[g * 4 + 3] = fmaxf(fmaf(xs.w, d2, a.w) + b1[g * 4 + 3], 0.f);
  }
  float acc[8] = {0.f, 0.f, 0.f, 0.f, 0.f, 0.f, 0.f, 0.f};
#pragma unroll
  for (int f = 0; f < 16; ++f)
#pragma unroll
    for (int j = 0; j < 8; ++j)
      acc[j] = fmaf(h[f], W2[f * 8 + j], acc[j]);  // uniform addr -> scalar loads
  *(float4*)(h1w2 + n * 8)     = make_float4(acc[0], acc[1], acc[2], acc[3]);
  *(float4*)(h1w2 + n * 8 + 4) = make_float4(acc[4], acc[5], acc[6], acc[7]);
}

// CSR gather layer 2: 2 lanes per node (lane q covers feats 4q..4q+3 of 8)
__global__ __launch_bounds__(256) void gather2_kernel(const int* __restrict__ srt,
                                                      const int* __restrict__ row_ofs,
                                                      const int* __restrict__ deg,
                                                      const float* __restrict__ dinv,
                                                      const float* __restrict__ h1w2,
                                                      float* __restrict__ agg2) {
  int t = blockIdx.x * 256 + threadIdx.x;
  int n = t >> 1, q = t & 1;
  if (n >= NN) return;
  int base = row_ofs[n], cnt = deg[n];
  float4 acc = make_float4(0.f, 0.f, 0.f, 0.f);
  for (int i = 0; i < cnt; ++i) {
    int s = srt[base + i];
    float w = dinv[s];
    float4 v = *(const float4*)(h1w2 + s * 8 + q * 4);
    acc = f4fma(w, v, acc);
  }
  float dn = dinv[n];
  acc.x *= dn; acc.y *= dn; acc.z *= dn; acc.w *= dn;
  *(float4*)(agg2 + n * 8 + q * 4) = acc;
}

// self-loop + bias + log_softmax(8)
__global__ __launch_bounds__(256) void final_kernel(const float* __restrict__ agg2,
                                                    const float* __restrict__ h1w2,
                                                    const float* __restrict__ dinv,
                                                    const float* __restrict__ b2,
                                                    float* __restrict__ out) {
  int n = blockIdx.x * 256 + threadIdx.x;
  if (n >= NN) return;
  float di = dinv[n], d2 = di * di;
  float4 a0 = *(const float4*)(agg2 + n * 8);
  float4 a1 = *(const float4*)(agg2 + n * 8 + 4);
  float4 s0 = *(const float4*)(h1w2 + n * 8);
  float4 s1 = *(const float4*)(h1w2 + n * 8 + 4);
  float v[8];
  v[0] = fmaf(s0.x, d2, a0.x) + b2[0];
  v[1] = fmaf(s0.y, d2, a0.y) + b2[1];
  v[2] = fmaf(s0.z, d2, a0.z) + b2[2];
  v[3] = fmaf(s0.w, d2, a0.w) + b2[3];
  v[4] = fmaf(s1.x, d2, a1.x) + b2[4];
  v[5] = fmaf(s1.y, d2, a1.y) + b2[5];
  v[6] = fmaf(s1.z, d2, a1.z) + b2[6];
  v[7] = fmaf(s1.w, d2, a1.w) + b2[7];
  float m = v[0];
#pragma unroll
  for (int j = 1; j < 8; ++j) m = fmaxf(m, v[j]);
  float sum = 0.f;
#pragma unroll
  for (int j = 0; j < 8; ++j) sum += expf(v[j] - m);
  float ls = m + logf(sum);
  *(float4*)(out + n * 8)     = make_float4(v[0] - ls, v[1] - ls, v[2] - ls, v[3] - ls);
  *(float4*)(out + n * 8 + 4) = make_float4(v[4] - ls, v[5] - ls, v[6] - ls, v[7] - ls);
}

// ---------- launch ----------
extern "C" void kernel_launch(void* const* d_in, const int* in_sizes, int n_in,
                              void* d_out, int out_size, void* d_ws, size_t ws_size,
                              hipStream_t stream) {
  const float* x  = (const float*)d_in[0];
  const int*   ei = (const int*)d_in[1];
  const float* W1 = (const float*)d_in[2];
  const float* b1 = (const float*)d_in[3];
  const float* W2 = (const float*)d_in[4];
  const float* b2 = (const float*)d_in[5];
  float* out = (float*)d_out;

  // ws layout: floats then ints; all offsets multiples of 16B (N*4 % 16 == 0)
  float* agg1    = (float*)d_ws;                 // 16N
  float* agg2    = agg1 + (size_t)16 * NN;       // 8N
  float* xw1     = agg2 + (size_t)8 * NN;        // 16N
  float* h1w2    = xw1 + (size_t)16 * NN;        // 8N
  float* dinv    = h1w2 + (size_t)8 * NN;        // N
  int*   deg     = (int*)(dinv + NN);            // N   <- memset from here
  int*   total   = deg + NN;                     // 4 (pad)
  int*   row_ofs = total + 4;                    // N
  int*   cursor  = row_ofs + NN;                 // N
  int*   flag    = cursor + NN;                  // 4 (pad)
  int*   srt     = flag + 4;                     // NE  (12.8 MB)

  hipMemsetAsync(deg, 0, (size_t)(NN + 4) * sizeof(int), stream);
  detect_kernel<<<1, 64, 0, stream>>>(ei, flag);
  deg_kernel<<<NE / 256, 256, 0, stream>>>(ei, deg, flag);
  dinv_kernel<<<(NN + 255) / 256, 256, 0, stream>>>(deg, dinv);
  alloc_kernel<<<(NN + 255) / 256, 256, 0, stream>>>(deg, row_ofs, cursor, total);
  scatter_kernel<<<NE / 256, 256, 0, stream>>>(ei, cursor, srt, flag);
  gemm1_kernel<<<NN / 4, 256, 0, stream>>>(x, W1, xw1);
  gather1_kernel<<<(4 * NN + 255) / 256, 256, 0, stream>>>(srt, row_ofs, deg, dinv, xw1, agg1);
  post1_kernel<<<(NN + 255) / 256, 256, 0, stream>>>(agg1, xw1, dinv, W2, b1, h1w2);
  gather2_kernel<<<(2 * NN + 255) / 256, 256, 0, stream>>>(srt, row_ofs, deg, dinv, h1w2, agg2);
  final_kernel<<<(NN + 255) / 256, 256, 0, stream>>>(agg2, h1w2, dinv, b2, out);
}

// Round 3
// 437.613 us; speedup vs baseline: 3.6878x; 1.6426x over previous
//
#include <hip/hip_runtime.h>

#define NN 100000
#define NE 3200000
#define NB 196        // coarse buckets: dst>>9, 512 nodes each
#define CAP 17408     // per-bucket pair capacity (mean 16384, +8 sigma)
#define PB 16         // edges per thread in bin_kernel
#define CH_A (256 * PB)

// ---------- helpers ----------
__device__ __forceinline__ float4 f4fma(float s, float4 a, float4 c) {
  c.x = fmaf(s, a.x, c.x); c.y = fmaf(s, a.y, c.y);
  c.z = fmaf(s, a.z, c.z); c.w = fmaf(s, a.w, c.w);
  return c;
}

template<int CTRL>
__device__ __forceinline__ float4 quad_bcast(float4 v) {
  float4 r;
  r.x = __int_as_float(__builtin_amdgcn_update_dpp(__float_as_int(v.x), __float_as_int(v.x), CTRL, 0xF, 0xF, false));
  r.y = __int_as_float(__builtin_amdgcn_update_dpp(__float_as_int(v.y), __float_as_int(v.y), CTRL, 0xF, 0xF, false));
  r.z = __int_as_float(__builtin_amdgcn_update_dpp(__float_as_int(v.z), __float_as_int(v.z), CTRL, 0xF, 0xF, false));
  r.w = __int_as_float(__builtin_amdgcn_update_dpp(__float_as_int(v.w), __float_as_int(v.w), CTRL, 0xF, 0xF, false));
  return r;
}

// edge_index may be int32 or int64 (values < 2^31, nonneg -> int64 high words are 0)
__device__ __forceinline__ int edge_val(const int* __restrict__ ei, int idx, bool w64) {
  return w64 ? ei[2 * idx] : ei[idx];
}

// ---------- kernels ----------
__global__ void detect_kernel(const int* __restrict__ ei, int* __restrict__ flag) {
  if (threadIdx.x == 0 && blockIdx.x == 0) {
    int o = 0;
    for (int i = 1; i < 64; i += 2) o |= ei[i];
    *flag = (o == 0) ? 1 : 0;   // 1 => int64 layout
  }
}

// Pass A: coarse-bucket edges. Per block: LDS histogram over 196 buckets,
// one global atomic per (block,bucket) to reserve space, then write (s,d)
// pairs into the bucket region (contiguous per block -> L2 write-combined).
__global__ __launch_bounds__(256) void bin_kernel(const int* __restrict__ ei,
                                                  int* __restrict__ bucket_cursor,
                                                  int2* __restrict__ pairs,
                                                  const int* __restrict__ flag) {
  __shared__ int cnt[NB];
  __shared__ int gb[NB];
  __shared__ int cur[NB];
  int t = threadIdx.x;
  if (t < NB) { cnt[t] = 0; cur[t] = 0; }
  __syncthreads();
  bool w64 = (*flag != 0);
  int base = blockIdx.x * CH_A;
  int s[PB], d[PB];
#pragma unroll
  for (int i = 0; i < PB; ++i) {
    int e = base + i * 256 + t;
    if (e < NE) {
      s[i] = edge_val(ei, e, w64);
      d[i] = edge_val(ei, NE + e, w64);
      atomicAdd(&cnt[d[i] >> 9], 1);
    } else {
      d[i] = -1;
    }
  }
  __syncthreads();
  if (t < NB && cnt[t] > 0) gb[t] = atomicAdd(&bucket_cursor[t], cnt[t]);
  __syncthreads();
#pragma unroll
  for (int i = 0; i < PB; ++i) {
    if (d[i] >= 0) {
      int b = d[i] >> 9;
      int pos = gb[b] + atomicAdd(&cur[b], 1);
      pairs[(size_t)b * CAP + pos] = make_int2(s[i], d[i]);
    }
  }
}

// exclusive scan of the 196 bucket counts (single block)
__global__ __launch_bounds__(256) void bscan_kernel(const int* __restrict__ bucket_cursor,
                                                    int* __restrict__ bucket_scan) {
  __shared__ int sc[256];
  __shared__ int orig[256];
  int t = threadIdx.x;
  int v = (t < NB) ? bucket_cursor[t] : 0;
  sc[t] = v; orig[t] = v;
  __syncthreads();
#pragma unroll
  for (int off = 1; off < 256; off <<= 1) {
    int u = (t >= off) ? sc[t - off] : 0;
    __syncthreads();
    sc[t] += u;
    __syncthreads();
  }
  if (t < NB) bucket_scan[t] = sc[t] - orig[t];
}

// Pass B: one block per bucket. Exact per-node histogram (512 LDS counters),
// LDS scan -> deg/row_ofs/dinv (coalesced), then scatter src into srt within
// a ~64KB window (L2 write-combined).
__global__ __launch_bounds__(256) void sort_kernel(const int2* __restrict__ pairs,
                                                   const int* __restrict__ bucket_cursor,
                                                   const int* __restrict__ bucket_scan,
                                                   int* __restrict__ srt,
                                                   int* __restrict__ deg,
                                                   int* __restrict__ row_ofs,
                                                   float* __restrict__ dinv) {
  __shared__ int hist[512];
  __shared__ int sc[512];
  __shared__ int cur[512];
  int t = threadIdx.x;
  int b = blockIdx.x;
  int cnt_b = bucket_cursor[b];
  size_t in_base = (size_t)b * CAP;
  int out_base = bucket_scan[b];
  hist[t] = 0; hist[t + 256] = 0;
  __syncthreads();
  for (int i = t; i < cnt_b; i += 256) {
    int2 p = pairs[in_base + i];
    atomicAdd(&hist[p.y & 511], 1);
  }
  __syncthreads();
  sc[t] = hist[t]; sc[t + 256] = hist[t + 256];
  __syncthreads();
#pragma unroll
  for (int off = 1; off < 512; off <<= 1) {
    int v0 = (t >= off) ? sc[t - off] : 0;
    int v1 = (t + 256 >= off) ? sc[t + 256 - off] : 0;
    __syncthreads();
    sc[t] += v0; sc[t + 256] += v1;
    __syncthreads();
  }
#pragma unroll
  for (int h = 0; h < 2; ++h) {
    int k = t + h * 256;
    int excl = sc[k] - hist[k];
    cur[k] = excl;
    int n = b * 512 + k;
    if (n < NN) {
      deg[n] = hist[k];
      row_ofs[n] = out_base + excl;
      dinv[n] = rsqrtf((float)hist[k] + 1.0f);  // +1 self loop
    }
  }
  __syncthreads();
  for (int i = t; i < cnt_b; i += 256) {
    int2 p = pairs[in_base + i];
    int pos = atomicAdd(&cur[p.y & 511], 1);
    srt[out_base + pos] = p.x;
  }
}

// xw1[n][16] = x[n][256] @ W1[256][16]; wave-per-node, W1 in registers.
__global__ __launch_bounds__(256) void gemm1_kernel(const float* __restrict__ x,
                                                    const float* __restrict__ W1,
                                                    float* __restrict__ xw1) {
  const int lane = threadIdx.x & 63;
  const int wv   = threadIdx.x >> 6;
  const int node = blockIdx.x * 4 + wv;
  const int cg = lane >> 2;
  const int jl = lane & 3;
  float4 w[16];
#pragma unroll
  for (int k = 0; k < 4; ++k)
#pragma unroll
    for (int c = 0; c < 4; ++c)
      w[k * 4 + c] = *(const float4*)(W1 + (cg * 16 + k * 4 + c) * 16 + jl * 4);
  if (node >= NN) return;
  float4 xv = *(const float4*)(x + (size_t)node * 256 + lane * 4);
  float4 acc = make_float4(0.f, 0.f, 0.f, 0.f);
  {
    float4 b = quad_bcast<0x00>(xv);
    acc = f4fma(b.x, w[0], acc);  acc = f4fma(b.y, w[1], acc);
    acc = f4fma(b.z, w[2], acc);  acc = f4fma(b.w, w[3], acc);
  }
  {
    float4 b = quad_bcast<0x55>(xv);
    acc = f4fma(b.x, w[4], acc);  acc = f4fma(b.y, w[5], acc);
    acc = f4fma(b.z, w[6], acc);  acc = f4fma(b.w, w[7], acc);
  }
  {
    float4 b = quad_bcast<0xAA>(xv);
    acc = f4fma(b.x, w[8], acc);  acc = f4fma(b.y, w[9], acc);
    acc = f4fma(b.z, w[10], acc); acc = f4fma(b.w, w[11], acc);
  }
  {
    float4 b = quad_bcast<0xFF>(xv);
    acc = f4fma(b.x, w[12], acc); acc = f4fma(b.y, w[13], acc);
    acc = f4fma(b.z, w[14], acc); acc = f4fma(b.w, w[15], acc);
  }
#pragma unroll
  for (int m = 4; m <= 32; m <<= 1) {
    acc.x += __shfl_xor(acc.x, m);
    acc.y += __shfl_xor(acc.y, m);
    acc.z += __shfl_xor(acc.z, m);
    acc.w += __shfl_xor(acc.w, m);
  }
  if (lane < 4)
    *(float4*)(xw1 + node * 16 + lane * 4) = acc;
}

// CSR gather layer 1: 4 lanes per node (lane q covers feats 4q..4q+3).
__global__ __launch_bounds__(256) void gather1_kernel(const int* __restrict__ srt,
                                                      const int* __restrict__ row_ofs,
                                                      const int* __restrict__ deg,
                                                      const float* __restrict__ dinv,
                                                      const float* __restrict__ xw1,
                                                      float* __restrict__ agg1) {
  int t = blockIdx.x * 256 + threadIdx.x;
  int n = t >> 2, q = t & 3;
  if (n >= NN) return;
  int base = row_ofs[n], cnt = deg[n];
  float4 acc = make_float4(0.f, 0.f, 0.f, 0.f);
  for (int i = 0; i < cnt; ++i) {
    int s = srt[base + i];
    float w = dinv[s];
    float4 v = *(const float4*)(xw1 + s * 16 + q * 4);
    acc = f4fma(w, v, acc);
  }
  float dn = dinv[n];
  acc.x *= dn; acc.y *= dn; acc.z *= dn; acc.w *= dn;
  *(float4*)(agg1 + n * 16 + q * 4) = acc;
}

// self-loop + bias + relu + h1 @ W2 (16x8) fused
__global__ __launch_bounds__(256) void post1_kernel(const float* __restrict__ agg1,
                                                    const float* __restrict__ xw1,
                                                    const float* __restrict__ dinv,
                                                    const float* __restrict__ W2,
                                                    const float* __restrict__ b1,
                                                    float* __restrict__ h1w2) {
  int n = blockIdx.x * 256 + threadIdx.x;
  if (n >= NN) return;
  float di = dinv[n], d2 = di * di;
  float h[16];
#pragma unroll
  for (int g = 0; g < 4; ++g) {
    float4 a  = *(const float4*)(agg1 + n * 16 + g * 4);
    float4 xs = *(const float4*)(xw1 + n * 16 + g * 4);
    h[g * 4 + 0] = fmaxf(fmaf(xs.x, d2, a.x) + b1[g * 4 + 0], 0.f);
    h[g * 4 + 1] = fmaxf(fmaf(xs.y, d2, a.y) + b1[g * 4 + 1], 0.f);
    h[g * 4 + 2] = fmaxf(fmaf(xs.z, d2, a.z) + b1[g * 4 + 2], 0.f);
    h[g * 4 + 3] = fmaxf(fmaf(xs.w, d2, a.w) + b1[g * 4 + 3], 0.f);
  }
  float acc[8] = {0.f, 0.f, 0.f, 0.f, 0.f, 0.f, 0.f, 0.f};
#pragma unroll
  for (int f = 0; f < 16; ++f)
#pragma unroll
    for (int j = 0; j < 8; ++j)
      acc[j] = fmaf(h[f], W2[f * 8 + j], acc[j]);  // uniform addr -> scalar loads
  *(float4*)(h1w2 + n * 8)     = make_float4(acc[0], acc[1], acc[2], acc[3]);
  *(float4*)(h1w2 + n * 8 + 4) = make_float4(acc[4], acc[5], acc[6], acc[7]);
}

// CSR gather layer 2: 2 lanes per node
__global__ __launch_bounds__(256) void gather2_kernel(const int* __restrict__ srt,
                                                      const int* __restrict__ row_ofs,
                                                      const int* __restrict__ deg,
                                                      const float* __restrict__ dinv,
                                                      const float* __restrict__ h1w2,
                                                      float* __restrict__ agg2) {
  int t = blockIdx.x * 256 + threadIdx.x;
  int n = t >> 1, q = t & 1;
  if (n >= NN) return;
  int base = row_ofs[n], cnt = deg[n];
  float4 acc = make_float4(0.f, 0.f, 0.f, 0.f);
  for (int i = 0; i < cnt; ++i) {
    int s = srt[base + i];
    float w = dinv[s];
    float4 v = *(const float4*)(h1w2 + s * 8 + q * 4);
    acc = f4fma(w, v, acc);
  }
  float dn = dinv[n];
  acc.x *= dn; acc.y *= dn; acc.z *= dn; acc.w *= dn;
  *(float4*)(agg2 + n * 8 + q * 4) = acc;
}

// self-loop + bias + log_softmax(8)
__global__ __launch_bounds__(256) void final_kernel(const float* __restrict__ agg2,
                                                    const float* __restrict__ h1w2,
                                                    const float* __restrict__ dinv,
                                                    const float* __restrict__ b2,
                                                    float* __restrict__ out) {
  int n = blockIdx.x * 256 + threadIdx.x;
  if (n >= NN) return;
  float di = dinv[n], d2 = di * di;
  float4 a0 = *(const float4*)(agg2 + n * 8);
  float4 a1 = *(const float4*)(agg2 + n * 8 + 4);
  float4 s0 = *(const float4*)(h1w2 + n * 8);
  float4 s1 = *(const float4*)(h1w2 + n * 8 + 4);
  float v[8];
  v[0] = fmaf(s0.x, d2, a0.x) + b2[0];
  v[1] = fmaf(s0.y, d2, a0.y) + b2[1];
  v[2] = fmaf(s0.z, d2, a0.z) + b2[2];
  v[3] = fmaf(s0.w, d2, a0.w) + b2[3];
  v[4] = fmaf(s1.x, d2, a1.x) + b2[4];
  v[5] = fmaf(s1.y, d2, a1.y) + b2[5];
  v[6] = fmaf(s1.z, d2, a1.z) + b2[6];
  v[7] = fmaf(s1.w, d2, a1.w) + b2[7];
  float m = v[0];
#pragma unroll
  for (int j = 1; j < 8; ++j) m = fmaxf(m, v[j]);
  float sum = 0.f;
#pragma unroll
  for (int j = 0; j < 8; ++j) sum += expf(v[j] - m);
  float ls = m + logf(sum);
  *(float4*)(out + n * 8)     = make_float4(v[0] - ls, v[1] - ls, v[2] - ls, v[3] - ls);
  *(float4*)(out + n * 8 + 4) = make_float4(v[4] - ls, v[5] - ls, v[6] - ls, v[7] - ls);
}

// ---------- launch ----------
extern "C" void kernel_launch(void* const* d_in, const int* in_sizes, int n_in,
                              void* d_out, int out_size, void* d_ws, size_t ws_size,
                              hipStream_t stream) {
  const float* x  = (const float*)d_in[0];
  const int*   ei = (const int*)d_in[1];
  const float* W1 = (const float*)d_in[2];
  const float* b1 = (const float*)d_in[3];
  const float* W2 = (const float*)d_in[4];
  const float* b2 = (const float*)d_in[5];
  float* out = (float*)d_out;

  // region0: pairs (27.3 MB) ALIASES the agg/xw1/h1w2 float block (19.2 MB).
  // Safe: pairs is dead after sort_kernel, floats are written only after it.
  const size_t region0_bytes = (size_t)NB * CAP * sizeof(int2);  // 27,295,744
  int2*  pairs   = (int2*)d_ws;
  float* agg1    = (float*)d_ws;                 // 16N
  float* agg2    = agg1 + (size_t)16 * NN;       // 8N
  float* xw1     = agg2 + (size_t)8 * NN;        // 16N
  float* h1w2    = xw1 + (size_t)16 * NN;        // 8N (ends at 19.2MB < region0)
  float* dinv    = (float*)((char*)d_ws + region0_bytes);  // N
  int*   deg     = (int*)(dinv + NN);            // N
  int*   row_ofs = deg + NN;                     // N
  int*   srt     = row_ofs + NN;                 // NE
  int*   bucket_cursor = srt + NE;               // 256 (memset)
  int*   bucket_scan   = bucket_cursor + 256;    // 256
  int*   flag          = bucket_scan + 256;      // 4

  hipMemsetAsync(bucket_cursor, 0, 256 * sizeof(int), stream);
  detect_kernel<<<1, 64, 0, stream>>>(ei, flag);
  bin_kernel<<<(NE + CH_A - 1) / CH_A, 256, 0, stream>>>(ei, bucket_cursor, pairs, flag);
  bscan_kernel<<<1, 256, 0, stream>>>(bucket_cursor, bucket_scan);
  sort_kernel<<<NB, 256, 0, stream>>>(pairs, bucket_cursor, bucket_scan, srt, deg, row_ofs, dinv);
  gemm1_kernel<<<NN / 4, 256, 0, stream>>>(x, W1, xw1);
  gather1_kernel<<<(4 * NN + 255) / 256, 256, 0, stream>>>(srt, row_ofs, deg, dinv, xw1, agg1);
  post1_kernel<<<(NN + 255) / 256, 256, 0, stream>>>(agg1, xw1, dinv, W2, b1, h1w2);
  gather2_kernel<<<(2 * NN + 255) / 256, 256, 0, stream>>>(srt, row_ofs, deg, dinv, h1w2, agg2);
  final_kernel<<<(NN + 255) / 256, 256, 0, stream>>>(agg2, h1w2, dinv, b2, out);
}

// Round 4
// 402.582 us; speedup vs baseline: 4.0087x; 1.0870x over previous
//
#include <hip/hip_runtime.h>

#define NN 100000
#define NE 3200000
#define NB 391        // coarse buckets: dst>>8, 256 nodes each
#define CAP 9216      // per-bucket pair capacity (mean 8184, sigma~90, +11 sigma)
#define PB 16         // edges per thread in bin_kernel
#define CH_A (256 * PB)

// ---------- helpers ----------
__device__ __forceinline__ float4 f4fma(float s, float4 a, float4 c) {
  c.x = fmaf(s, a.x, c.x); c.y = fmaf(s, a.y, c.y);
  c.z = fmaf(s, a.z, c.z); c.w = fmaf(s, a.w, c.w);
  return c;
}

template<int CTRL>
__device__ __forceinline__ float4 quad_bcast(float4 v) {
  float4 r;
  r.x = __int_as_float(__builtin_amdgcn_update_dpp(__float_as_int(v.x), __float_as_int(v.x), CTRL, 0xF, 0xF, false));
  r.y = __int_as_float(__builtin_amdgcn_update_dpp(__float_as_int(v.y), __float_as_int(v.y), CTRL, 0xF, 0xF, false));
  r.z = __int_as_float(__builtin_amdgcn_update_dpp(__float_as_int(v.z), __float_as_int(v.z), CTRL, 0xF, 0xF, false));
  r.w = __int_as_float(__builtin_amdgcn_update_dpp(__float_as_int(v.w), __float_as_int(v.w), CTRL, 0xF, 0xF, false));
  return r;
}

// edge_index may be int32 or int64 (values < 2^31, nonneg -> int64 high words are 0)
__device__ __forceinline__ int edge_val(const int* __restrict__ ei, int idx, bool w64) {
  return w64 ? ei[2 * idx] : ei[idx];
}

// ---------- kernels ----------
__global__ void detect_kernel(const int* __restrict__ ei, int* __restrict__ flag) {
  if (threadIdx.x == 0 && blockIdx.x == 0) {
    int o = 0;
    for (int i = 1; i < 64; i += 2) o |= ei[i];
    *flag = (o == 0) ? 1 : 0;   // 1 => int64 layout
  }
}

// Pass A: coarse-bucket edges. Per-WAVE private LDS histograms (no cross-wave
// contention), one global atomic per (block,bucket), per-wave sub-ranges so
// the scatter atomics also stay wave-private.
__global__ __launch_bounds__(256) void bin_kernel(const int* __restrict__ ei,
                                                  int* __restrict__ bucket_cursor,
                                                  int2* __restrict__ pairs,
                                                  const int* __restrict__ flag) {
  __shared__ int cnt[4][NB];
  __shared__ int wbase[4][NB];   // absolute write cursor per wave per bucket
  int t = threadIdx.x;
  int wv = t >> 6;
  for (int k = t; k < 4 * NB; k += 256) (&cnt[0][0])[k] = 0;
  __syncthreads();
  bool w64 = (*flag != 0);
  int base = blockIdx.x * CH_A;
  int s[PB], d[PB];
#pragma unroll
  for (int i = 0; i < PB; ++i) {
    int e = base + i * 256 + t;
    if (e < NE) {
      s[i] = edge_val(ei, e, w64);
      d[i] = edge_val(ei, NE + e, w64);
      atomicAdd(&cnt[wv][d[i] >> 8], 1);
    } else {
      d[i] = -1;
    }
  }
  __syncthreads();
  for (int b = t; b < NB; b += 256) {
    int c0 = cnt[0][b], c1 = cnt[1][b], c2 = cnt[2][b], c3 = cnt[3][b];
    int tot = c0 + c1 + c2 + c3;
    int g = (tot > 0) ? atomicAdd(&bucket_cursor[b], tot) : 0;
    wbase[0][b] = g;
    wbase[1][b] = g + c0;
    wbase[2][b] = g + c0 + c1;
    wbase[3][b] = g + c0 + c1 + c2;
  }
  __syncthreads();
#pragma unroll
  for (int i = 0; i < PB; ++i) {
    if (d[i] >= 0) {
      int b = d[i] >> 8;
      int pos = atomicAdd(&wbase[wv][b], 1);
      pairs[(size_t)b * CAP + pos] = make_int2(s[i], d[i]);
    }
  }
}

// exclusive scan of NB (<=512) bucket counts, single block of 256
__global__ __launch_bounds__(256) void bscan_kernel(const int* __restrict__ bucket_cursor,
                                                    int* __restrict__ bucket_scan) {
  __shared__ int sc[512];
  __shared__ int orig[512];
  int t = threadIdx.x;
  int v0 = (t < NB) ? bucket_cursor[t] : 0;
  int v1 = (t + 256 < NB) ? bucket_cursor[t + 256] : 0;
  sc[t] = v0; orig[t] = v0;
  sc[t + 256] = v1; orig[t + 256] = v1;
  __syncthreads();
#pragma unroll
  for (int off = 1; off < 512; off <<= 1) {
    int u0 = (t >= off) ? sc[t - off] : 0;
    int u1 = (t + 256 >= off) ? sc[t + 256 - off] : 0;
    __syncthreads();
    sc[t] += u0; sc[t + 256] += u1;
    __syncthreads();
  }
  if (t < NB) bucket_scan[t] = sc[t] - orig[t];
  if (t + 256 < NB) bucket_scan[t + 256] = sc[t + 256] - orig[t + 256];
}

// Pass B: one block per 256-node bucket. Exact per-node histogram, scan ->
// deg/row_ofs/dinv, scatter src into srt within a ~32KB window.
__global__ __launch_bounds__(256) void sort_kernel(const int2* __restrict__ pairs,
                                                   const int* __restrict__ bucket_cursor,
                                                   const int* __restrict__ bucket_scan,
                                                   int* __restrict__ srt,
                                                   int* __restrict__ deg,
                                                   int* __restrict__ row_ofs,
                                                   float* __restrict__ dinv) {
  __shared__ int hist[256];
  __shared__ int sc[256];
  __shared__ int cur[256];
  int t = threadIdx.x;
  int b = blockIdx.x;
  int cnt_b = bucket_cursor[b];
  size_t in_base = (size_t)b * CAP;
  int out_base = bucket_scan[b];
  hist[t] = 0;
  __syncthreads();
  for (int i = t; i < cnt_b; i += 256) {
    int2 p = pairs[in_base + i];
    atomicAdd(&hist[p.y & 255], 1);
  }
  __syncthreads();
  sc[t] = hist[t];
  __syncthreads();
#pragma unroll
  for (int off = 1; off < 256; off <<= 1) {
    int u = (t >= off) ? sc[t - off] : 0;
    __syncthreads();
    sc[t] += u;
    __syncthreads();
  }
  {
    int excl = sc[t] - hist[t];
    cur[t] = out_base + excl;
    int n = b * 256 + t;
    if (n < NN) {
      deg[n] = hist[t];
      row_ofs[n] = out_base + excl;
      dinv[n] = rsqrtf((float)hist[t] + 1.0f);  // +1 self loop
    }
  }
  __syncthreads();
  for (int i = t; i < cnt_b; i += 256) {
    int2 p = pairs[in_base + i];
    int pos = atomicAdd(&cur[p.y & 255], 1);
    srt[pos] = p.x;
  }
}

// xw1[n][16] = x[n][256] @ W1[256][16]; wave handles 4 nodes per pass
// (4 loads in flight, 4 independent fma chains). Grid: NN/16 blocks exact.
__global__ __launch_bounds__(256) void gemm1_kernel(const float* __restrict__ x,
                                                    const float* __restrict__ W1,
                                                    float* __restrict__ xw1) {
  const int lane = threadIdx.x & 63;
  const int wv   = threadIdx.x >> 6;
  const int node0 = (blockIdx.x * 4 + wv) * 4;
  const int cg = lane >> 2;
  const int jl = lane & 3;
  float4 w[16];
#pragma unroll
  for (int k = 0; k < 4; ++k)
#pragma unroll
    for (int c = 0; c < 4; ++c)
      w[k * 4 + c] = *(const float4*)(W1 + (cg * 16 + k * 4 + c) * 16 + jl * 4);
  float4 xv[4];
#pragma unroll
  for (int i = 0; i < 4; ++i)
    xv[i] = *(const float4*)(x + (size_t)(node0 + i) * 256 + lane * 4);
  float4 acc[4];
#pragma unroll
  for (int i = 0; i < 4; ++i) acc[i] = make_float4(0.f, 0.f, 0.f, 0.f);
#pragma unroll
  for (int i = 0; i < 4; ++i) {
    float4 b = quad_bcast<0x00>(xv[i]);
    acc[i] = f4fma(b.x, w[0], acc[i]);  acc[i] = f4fma(b.y, w[1], acc[i]);
    acc[i] = f4fma(b.z, w[2], acc[i]);  acc[i] = f4fma(b.w, w[3], acc[i]);
  }
#pragma unroll
  for (int i = 0; i < 4; ++i) {
    float4 b = quad_bcast<0x55>(xv[i]);
    acc[i] = f4fma(b.x, w[4], acc[i]);  acc[i] = f4fma(b.y, w[5], acc[i]);
    acc[i] = f4fma(b.z, w[6], acc[i]);  acc[i] = f4fma(b.w, w[7], acc[i]);
  }
#pragma unroll
  for (int i = 0; i < 4; ++i) {
    float4 b = quad_bcast<0xAA>(xv[i]);
    acc[i] = f4fma(b.x, w[8], acc[i]);  acc[i] = f4fma(b.y, w[9], acc[i]);
    acc[i] = f4fma(b.z, w[10], acc[i]); acc[i] = f4fma(b.w, w[11], acc[i]);
  }
#pragma unroll
  for (int i = 0; i < 4; ++i) {
    float4 b = quad_bcast<0xFF>(xv[i]);
    acc[i] = f4fma(b.x, w[12], acc[i]); acc[i] = f4fma(b.y, w[13], acc[i]);
    acc[i] = f4fma(b.z, w[14], acc[i]); acc[i] = f4fma(b.w, w[15], acc[i]);
  }
#pragma unroll
  for (int m = 4; m <= 32; m <<= 1) {
#pragma unroll
    for (int i = 0; i < 4; ++i) {
      acc[i].x += __shfl_xor(acc[i].x, m);
      acc[i].y += __shfl_xor(acc[i].y, m);
      acc[i].z += __shfl_xor(acc[i].z, m);
      acc[i].w += __shfl_xor(acc[i].w, m);
    }
  }
  if (lane < 4) {
#pragma unroll
    for (int i = 0; i < 4; ++i)
      *(float4*)(xw1 + (node0 + i) * 16 + lane * 4) = acc[i];
  }
}

// CSR gather layer 1: 4 lanes per node; srt prefetch software-pipelined.
__global__ __launch_bounds__(256) void gather1_kernel(const int* __restrict__ srt,
                                                      const int* __restrict__ row_ofs,
                                                      const int* __restrict__ deg,
                                                      const float* __restrict__ dinv,
                                                      const float* __restrict__ xw1,
                                                      float* __restrict__ agg1) {
  int t = blockIdx.x * 256 + threadIdx.x;
  int n = t >> 2, q = t & 3;
  if (n >= NN) return;
  int base = row_ofs[n], cnt = deg[n];
  float4 acc = make_float4(0.f, 0.f, 0.f, 0.f);
  int s_next = (cnt > 0) ? srt[base] : 0;
  for (int i = 0; i < cnt; ++i) {
    int s = s_next;
    if (i + 1 < cnt) s_next = srt[base + i + 1];
    float w = dinv[s];
    float4 v = *(const float4*)(xw1 + s * 16 + q * 4);
    acc = f4fma(w, v, acc);
  }
  float dn = dinv[n];
  acc.x *= dn; acc.y *= dn; acc.z *= dn; acc.w *= dn;
  *(float4*)(agg1 + n * 16 + q * 4) = acc;
}

// self-loop + bias + relu + h1 @ W2 (16x8) fused
__global__ __launch_bounds__(256) void post1_kernel(const float* __restrict__ agg1,
                                                    const float* __restrict__ xw1,
                                                    const float* __restrict__ dinv,
                                                    const float* __restrict__ W2,
                                                    const float* __restrict__ b1,
                                                    float* __restrict__ h1w2) {
  int n = blockIdx.x * 256 + threadIdx.x;
  if (n >= NN) return;
  float di = dinv[n], d2 = di * di;
  float h[16];
#pragma unroll
  for (int g = 0; g < 4; ++g) {
    float4 a  = *(const float4*)(agg1 + n * 16 + g * 4);
    float4 xs = *(const float4*)(xw1 + n * 16 + g * 4);
    h[g * 4 + 0] = fmaxf(fmaf(xs.x, d2, a.x) + b1[g * 4 + 0], 0.f);
    h[g * 4 + 1] = fmaxf(fmaf(xs.y, d2, a.y) + b1[g * 4 + 1], 0.f);
    h[g * 4 + 2] = fmaxf(fmaf(xs.z, d2, a.z) + b1[g * 4 + 2], 0.f);
    h[g * 4 + 3] = fmaxf(fmaf(xs.w, d2, a.w) + b1[g * 4 + 3], 0.f);
  }
  float acc[8] = {0.f, 0.f, 0.f, 0.f, 0.f, 0.f, 0.f, 0.f};
#pragma unroll
  for (int f = 0; f < 16; ++f)
#pragma unroll
    for (int j = 0; j < 8; ++j)
      acc[j] = fmaf(h[f], W2[f * 8 + j], acc[j]);  // uniform addr -> scalar loads
  *(float4*)(h1w2 + n * 8)     = make_float4(acc[0], acc[1], acc[2], acc[3]);
  *(float4*)(h1w2 + n * 8 + 4) = make_float4(acc[4], acc[5], acc[6], acc[7]);
}

// CSR gather layer 2: 2 lanes per node
__global__ __launch_bounds__(256) void gather2_kernel(const int* __restrict__ srt,
                                                      const int* __restrict__ row_ofs,
                                                      const int* __restrict__ deg,
                                                      const float* __restrict__ dinv,
                                                      const float* __restrict__ h1w2,
                                                      float* __restrict__ agg2) {
  int t = blockIdx.x * 256 + threadIdx.x;
  int n = t >> 1, q = t & 1;
  if (n >= NN) return;
  int base = row_ofs[n], cnt = deg[n];
  float4 acc = make_float4(0.f, 0.f, 0.f, 0.f);
  int s_next = (cnt > 0) ? srt[base] : 0;
  for (int i = 0; i < cnt; ++i) {
    int s = s_next;
    if (i + 1 < cnt) s_next = srt[base + i + 1];
    float w = dinv[s];
    float4 v = *(const float4*)(h1w2 + s * 8 + q * 4);
    acc = f4fma(w, v, acc);
  }
  float dn = dinv[n];
  acc.x *= dn; acc.y *= dn; acc.z *= dn; acc.w *= dn;
  *(float4*)(agg2 + n * 8 + q * 4) = acc;
}

// self-loop + bias + log_softmax(8)
__global__ __launch_bounds__(256) void final_kernel(const float* __restrict__ agg2,
                                                    const float* __restrict__ h1w2,
                                                    const float* __restrict__ dinv,
                                                    const float* __restrict__ b2,
                                                    float* __restrict__ out) {
  int n = blockIdx.x * 256 + threadIdx.x;
  if (n >= NN) return;
  float di = dinv[n], d2 = di * di;
  float4 a0 = *(const float4*)(agg2 + n * 8);
  float4 a1 = *(const float4*)(agg2 + n * 8 + 4);
  float4 s0 = *(const float4*)(h1w2 + n * 8);
  float4 s1 = *(const float4*)(h1w2 + n * 8 + 4);
  float v[8];
  v[0] = fmaf(s0.x, d2, a0.x) + b2[0];
  v[1] = fmaf(s0.y, d2, a0.y) + b2[1];
  v[2] = fmaf(s0.z, d2, a0.z) + b2[2];
  v[3] = fmaf(s0.w, d2, a0.w) + b2[3];
  v[4] = fmaf(s1.x, d2, a1.x) + b2[4];
  v[5] = fmaf(s1.y, d2, a1.y) + b2[5];
  v[6] = fmaf(s1.z, d2, a1.z) + b2[6];
  v[7] = fmaf(s1.w, d2, a1.w) + b2[7];
  float m = v[0];
#pragma unroll
  for (int j = 1; j < 8; ++j) m = fmaxf(m, v[j]);
  float sum = 0.f;
#pragma unroll
  for (int j = 0; j < 8; ++j) sum += expf(v[j] - m);
  float ls = m + logf(sum);
  *(float4*)(out + n * 8)     = make_float4(v[0] - ls, v[1] - ls, v[2] - ls, v[3] - ls);
  *(float4*)(out + n * 8 + 4) = make_float4(v[4] - ls, v[5] - ls, v[6] - ls, v[7] - ls);
}

// ---------- launch ----------
extern "C" void kernel_launch(void* const* d_in, const int* in_sizes, int n_in,
                              void* d_out, int out_size, void* d_ws, size_t ws_size,
                              hipStream_t stream) {
  const float* x  = (const float*)d_in[0];
  const int*   ei = (const int*)d_in[1];
  const float* W1 = (const float*)d_in[2];
  const float* b1 = (const float*)d_in[3];
  const float* W2 = (const float*)d_in[4];
  const float* b2 = (const float*)d_in[5];
  float* out = (float*)d_out;

  // region0: pairs (28.8 MB) ALIASES the agg/xw1/h1w2 float block (19.2 MB).
  // Safe: pairs is dead after sort_kernel; floats written only after it.
  const size_t region0_bytes = (size_t)NB * CAP * sizeof(int2);
  int2*  pairs   = (int2*)d_ws;
  float* agg1    = (float*)d_ws;                 // 16N
  float* agg2    = agg1 + (size_t)16 * NN;       // 8N
  float* xw1     = agg2 + (size_t)8 * NN;        // 16N
  float* h1w2    = xw1 + (size_t)16 * NN;        // 8N (ends at 19.2MB < region0)
  float* dinv    = (float*)((char*)d_ws + region0_bytes);  // N
  int*   deg     = (int*)(dinv + NN);            // N
  int*   row_ofs = deg + NN;                     // N
  int*   srt     = row_ofs + NN;                 // NE
  int*   bucket_cursor = srt + NE;               // NB (memset)
  int*   bucket_scan   = bucket_cursor + NB + 1; // NB
  int*   flag          = bucket_scan + NB + 1;   // 1

  hipMemsetAsync(bucket_cursor, 0, NB * sizeof(int), stream);
  detect_kernel<<<1, 64, 0, stream>>>(ei, flag);
  bin_kernel<<<(NE + CH_A - 1) / CH_A, 256, 0, stream>>>(ei, bucket_cursor, pairs, flag);
  bscan_kernel<<<1, 256, 0, stream>>>(bucket_cursor, bucket_scan);
  sort_kernel<<<NB, 256, 0, stream>>>(pairs, bucket_cursor, bucket_scan, srt, deg, row_ofs, dinv);
  gemm1_kernel<<<NN / 16, 256, 0, stream>>>(x, W1, xw1);
  gather1_kernel<<<(4 * NN + 255) / 256, 256, 0, stream>>>(srt, row_ofs, deg, dinv, xw1, agg1);
  post1_kernel<<<(NN + 255) / 256, 256, 0, stream>>>(agg1, xw1, dinv, W2, b1, h1w2);
  gather2_kernel<<<(2 * NN + 255) / 256, 256, 0, stream>>>(srt, row_ofs, deg, dinv, h1w2, agg2);
  final_kernel<<<(NN + 255) / 256, 256, 0, stream>>>(agg2, h1w2, dinv, b2, out);
}

// Round 5
// 337.403 us; speedup vs baseline: 4.7831x; 1.1932x over previous
//
#include <hip/hip_runtime.h>

#define NN 100000
#define NE 3200000
#define NB 391        // coarse buckets: dst>>8, 256 nodes each
#define CAP 9216      // per-bucket pair capacity (mean 8184, sigma~90, +11 sigma)
#define PB 16         // edges per thread in bin_kernel
#define CH_A (256 * PB)

// ---------- helpers ----------
__device__ __forceinline__ float4 f4add(float4 a, float4 b) {
  return make_float4(a.x + b.x, a.y + b.y, a.z + b.z, a.w + b.w);
}
__device__ __forceinline__ float4 f4fma(float s, float4 a, float4 c) {
  c.x = fmaf(s, a.x, c.x); c.y = fmaf(s, a.y, c.y);
  c.z = fmaf(s, a.z, c.z); c.w = fmaf(s, a.w, c.w);
  return c;
}

template<int CTRL>
__device__ __forceinline__ float4 quad_bcast(float4 v) {
  float4 r;
  r.x = __int_as_float(__builtin_amdgcn_update_dpp(__float_as_int(v.x), __float_as_int(v.x), CTRL, 0xF, 0xF, false));
  r.y = __int_as_float(__builtin_amdgcn_update_dpp(__float_as_int(v.y), __float_as_int(v.y), CTRL, 0xF, 0xF, false));
  r.z = __int_as_float(__builtin_amdgcn_update_dpp(__float_as_int(v.z), __float_as_int(v.z), CTRL, 0xF, 0xF, false));
  r.w = __int_as_float(__builtin_amdgcn_update_dpp(__float_as_int(v.w), __float_as_int(v.w), CTRL, 0xF, 0xF, false));
  return r;
}

// edge_index may be int32 or int64 (values < 2^31, nonneg -> int64 high words are 0)
__device__ __forceinline__ int edge_val(const int* __restrict__ ei, int idx, bool w64) {
  return w64 ? ei[2 * idx] : ei[idx];
}

// ---------- kernels ----------
__global__ void detect_kernel(const int* __restrict__ ei, int* __restrict__ flag) {
  if (threadIdx.x == 0 && blockIdx.x == 0) {
    int o = 0;
    for (int i = 1; i < 64; i += 2) o |= ei[i];
    *flag = (o == 0) ? 1 : 0;   // 1 => int64 layout
  }
}

// Pass A: coarse-bucket edges with COALESCED global writes.
// Per-wave LDS histograms -> block scan over buckets -> stage all 4096 edges
// into LDS sorted by bucket -> linear sweep writes contiguous per-bucket runs.
__global__ __launch_bounds__(256) void bin_kernel(const int* __restrict__ ei,
                                                  int* __restrict__ bucket_cursor,
                                                  int2* __restrict__ pairs,
                                                  const int* __restrict__ flag) {
  __shared__ int  cnt[4][NB];
  __shared__ int  wcur[4][NB];   // per-wave staging cursor (block-local slot)
  __shared__ int  lbase[NB];     // block-local exclusive scan of bucket totals
  __shared__ int  gbase[NB];     // reserved base within bucket region
  __shared__ int  sc[512];
  __shared__ int2 stage[CH_A];   // 32 KB
  int t = threadIdx.x;
  int wv = t >> 6;
  for (int k = t; k < 4 * NB; k += 256) (&cnt[0][0])[k] = 0;
  __syncthreads();
  bool w64 = (*flag != 0);
  int base = blockIdx.x * CH_A;
  int nval = min(CH_A, NE - base);
  int s[PB], d[PB];
#pragma unroll
  for (int i = 0; i < PB; ++i) {
    int e = base + i * 256 + t;
    if (e < NE) {
      s[i] = edge_val(ei, e, w64);
      d[i] = edge_val(ei, NE + e, w64);
      atomicAdd(&cnt[wv][d[i] >> 8], 1);
    } else {
      d[i] = -1;
    }
  }
  __syncthreads();
  // block scan over bucket totals (512-wide, 2 per thread)
  int tA = (t < NB) ? cnt[0][t] + cnt[1][t] + cnt[2][t] + cnt[3][t] : 0;
  int tB = (t + 256 < NB) ? cnt[0][t + 256] + cnt[1][t + 256] + cnt[2][t + 256] + cnt[3][t + 256] : 0;
  sc[t] = tA; sc[t + 256] = tB;
  __syncthreads();
#pragma unroll
  for (int off = 1; off < 512; off <<= 1) {
    int u0 = (t >= off) ? sc[t - off] : 0;
    int u1 = (t + 256 >= off) ? sc[t + 256 - off] : 0;
    __syncthreads();
    sc[t] += u0; sc[t + 256] += u1;
    __syncthreads();
  }
#pragma unroll
  for (int h = 0; h < 2; ++h) {
    int k = t + h * 256;
    if (k < NB) {
      int tot = (h == 0) ? tA : tB;
      int lb = sc[k] - tot;
      lbase[k] = lb;
      gbase[k] = (tot > 0) ? atomicAdd(&bucket_cursor[k], tot) : 0;
      int c0 = cnt[0][k], c1 = cnt[1][k], c2 = cnt[2][k];
      wcur[0][k] = lb;
      wcur[1][k] = lb + c0;
      wcur[2][k] = lb + c0 + c1;
      wcur[3][k] = lb + c0 + c1 + c2;
    }
  }
  __syncthreads();
#pragma unroll
  for (int i = 0; i < PB; ++i) {
    if (d[i] >= 0) {
      int b = d[i] >> 8;
      int slot = atomicAdd(&wcur[wv][b], 1);
      stage[slot] = make_int2(s[i], d[i]);
    }
  }
  __syncthreads();
  // coalesced-ish writeout: consecutive k are runs within one bucket
  for (int k = t; k < nval; k += 256) {
    int2 p = stage[k];
    int b = p.y >> 8;
    pairs[(size_t)b * CAP + gbase[b] + (k - lbase[b])] = p;
  }
}

// exclusive scan of NB (<=512) bucket counts, single block of 256
__global__ __launch_bounds__(256) void bscan_kernel(const int* __restrict__ bucket_cursor,
                                                    int* __restrict__ bucket_scan) {
  __shared__ int sc[512];
  __shared__ int orig[512];
  int t = threadIdx.x;
  int v0 = (t < NB) ? bucket_cursor[t] : 0;
  int v1 = (t + 256 < NB) ? bucket_cursor[t + 256] : 0;
  sc[t] = v0; orig[t] = v0;
  sc[t + 256] = v1; orig[t + 256] = v1;
  __syncthreads();
#pragma unroll
  for (int off = 1; off < 512; off <<= 1) {
    int u0 = (t >= off) ? sc[t - off] : 0;
    int u1 = (t + 256 >= off) ? sc[t + 256 - off] : 0;
    __syncthreads();
    sc[t] += u0; sc[t + 256] += u1;
    __syncthreads();
  }
  if (t < NB) bucket_scan[t] = sc[t] - orig[t];
  if (t + 256 < NB) bucket_scan[t + 256] = sc[t + 256] - orig[t + 256];
}

// Pass B: one block per 256-node bucket. Exact per-node histogram, scan ->
// deg/row_ofs/dinv, scatter src into srt within a ~32KB window.
__global__ __launch_bounds__(256) void sort_kernel(const int2* __restrict__ pairs,
                                                   const int* __restrict__ bucket_cursor,
                                                   const int* __restrict__ bucket_scan,
                                                   int* __restrict__ srt,
                                                   int* __restrict__ deg,
                                                   int* __restrict__ row_ofs,
                                                   float* __restrict__ dinv) {
  __shared__ int hist[256];
  __shared__ int sc[256];
  __shared__ int cur[256];
  int t = threadIdx.x;
  int b = blockIdx.x;
  int cnt_b = bucket_cursor[b];
  size_t in_base = (size_t)b * CAP;
  int out_base = bucket_scan[b];
  hist[t] = 0;
  __syncthreads();
  for (int i = t; i < cnt_b; i += 256) {
    int2 p = pairs[in_base + i];
    atomicAdd(&hist[p.y & 255], 1);
  }
  __syncthreads();
  sc[t] = hist[t];
  __syncthreads();
#pragma unroll
  for (int off = 1; off < 256; off <<= 1) {
    int u = (t >= off) ? sc[t - off] : 0;
    __syncthreads();
    sc[t] += u;
    __syncthreads();
  }
  {
    int excl = sc[t] - hist[t];
    cur[t] = out_base + excl;
    int n = b * 256 + t;
    if (n < NN) {
      deg[n] = hist[t];
      row_ofs[n] = out_base + excl;
      dinv[n] = rsqrtf((float)hist[t] + 1.0f);  // +1 self loop
    }
  }
  __syncthreads();
  for (int i = t; i < cnt_b; i += 256) {
    int2 p = pairs[in_base + i];
    int pos = atomicAdd(&cur[p.y & 255], 1);
    srt[pos] = p.x;
  }
}

// xw1s[n][16] = dinv[n] * (x[n][256] @ W1[256][16]); wave handles 4 nodes/pass.
__global__ __launch_bounds__(256) void gemm1_kernel(const float* __restrict__ x,
                                                    const float* __restrict__ W1,
                                                    const float* __restrict__ dinv,
                                                    float* __restrict__ xw1s) {
  const int lane = threadIdx.x & 63;
  const int wv   = threadIdx.x >> 6;
  const int node0 = (blockIdx.x * 4 + wv) * 4;
  const int cg = lane >> 2;
  const int jl = lane & 3;
  float4 w[16];
#pragma unroll
  for (int k = 0; k < 4; ++k)
#pragma unroll
    for (int c = 0; c < 4; ++c)
      w[k * 4 + c] = *(const float4*)(W1 + (cg * 16 + k * 4 + c) * 16 + jl * 4);
  float4 xv[4];
#pragma unroll
  for (int i = 0; i < 4; ++i)
    xv[i] = *(const float4*)(x + (size_t)(node0 + i) * 256 + lane * 4);
  float4 acc[4];
#pragma unroll
  for (int i = 0; i < 4; ++i) acc[i] = make_float4(0.f, 0.f, 0.f, 0.f);
#pragma unroll
  for (int i = 0; i < 4; ++i) {
    float4 b = quad_bcast<0x00>(xv[i]);
    acc[i] = f4fma(b.x, w[0], acc[i]);  acc[i] = f4fma(b.y, w[1], acc[i]);
    acc[i] = f4fma(b.z, w[2], acc[i]);  acc[i] = f4fma(b.w, w[3], acc[i]);
  }
#pragma unroll
  for (int i = 0; i < 4; ++i) {
    float4 b = quad_bcast<0x55>(xv[i]);
    acc[i] = f4fma(b.x, w[4], acc[i]);  acc[i] = f4fma(b.y, w[5], acc[i]);
    acc[i] = f4fma(b.z, w[6], acc[i]);  acc[i] = f4fma(b.w, w[7], acc[i]);
  }
#pragma unroll
  for (int i = 0; i < 4; ++i) {
    float4 b = quad_bcast<0xAA>(xv[i]);
    acc[i] = f4fma(b.x, w[8], acc[i]);  acc[i] = f4fma(b.y, w[9], acc[i]);
    acc[i] = f4fma(b.z, w[10], acc[i]); acc[i] = f4fma(b.w, w[11], acc[i]);
  }
#pragma unroll
  for (int i = 0; i < 4; ++i) {
    float4 b = quad_bcast<0xFF>(xv[i]);
    acc[i] = f4fma(b.x, w[12], acc[i]); acc[i] = f4fma(b.y, w[13], acc[i]);
    acc[i] = f4fma(b.z, w[14], acc[i]); acc[i] = f4fma(b.w, w[15], acc[i]);
  }
#pragma unroll
  for (int m = 4; m <= 32; m <<= 1) {
#pragma unroll
    for (int i = 0; i < 4; ++i) {
      acc[i].x += __shfl_xor(acc[i].x, m);
      acc[i].y += __shfl_xor(acc[i].y, m);
      acc[i].z += __shfl_xor(acc[i].z, m);
      acc[i].w += __shfl_xor(acc[i].w, m);
    }
  }
  if (lane < 4) {
#pragma unroll
    for (int i = 0; i < 4; ++i) {
      float dn = dinv[node0 + i];
      float4 a = acc[i];
      a.x *= dn; a.y *= dn; a.z *= dn; a.w *= dn;
      *(float4*)(xw1s + (node0 + i) * 16 + lane * 4) = a;
    }
  }
}

// Layer 1 fused: gather(xw1s) + self-loop + bias + relu + @W2, pre-scaled out.
// 8 lanes per node: q = feat group (4 feats), e = edge half.
__global__ __launch_bounds__(256) void layer1_kernel(const int* __restrict__ srt,
                                                     const int* __restrict__ row_ofs,
                                                     const int* __restrict__ deg,
                                                     const float* __restrict__ dinv,
                                                     const float* __restrict__ xw1s,
                                                     const float* __restrict__ W2,
                                                     const float* __restrict__ b1,
                                                     float* __restrict__ h1w2s) {
  int t = blockIdx.x * 256 + threadIdx.x;
  int n = t >> 3, sub = t & 7, q = sub & 3, e = sub >> 2;
  if (n >= NN) return;
  int base = row_ofs[n], cnt = deg[n];
  int half = cnt >> 1;
  int i0 = e ? half : 0;
  int i1 = e ? cnt : half;
  float4 acc = make_float4(0.f, 0.f, 0.f, 0.f);
  int s_next = (i0 < i1) ? srt[base + i0] : 0;
  for (int i = i0; i < i1; ++i) {
    int s = s_next;
    if (i + 1 < i1) s_next = srt[base + i + 1];
    acc = f4add(acc, *(const float4*)(xw1s + s * 16 + q * 4));
  }
  // combine edge halves (xor lane bit 2)
  acc.x += __shfl_xor(acc.x, 4);
  acc.y += __shfl_xor(acc.y, 4);
  acc.z += __shfl_xor(acc.z, 4);
  acc.w += __shfl_xor(acc.w, 4);
  float dn = dinv[n];
  float4 sv = *(const float4*)(xw1s + n * 16 + q * 4);
  float4 bv = *(const float4*)(b1 + q * 4);
  float h[4];
  h[0] = fmaxf(fmaf(dn, acc.x + sv.x, bv.x), 0.f);
  h[1] = fmaxf(fmaf(dn, acc.y + sv.y, bv.y), 0.f);
  h[2] = fmaxf(fmaf(dn, acc.z + sv.z, bv.z), 0.f);
  h[3] = fmaxf(fmaf(dn, acc.w + sv.w, bv.w), 0.f);
  float p[8] = {0.f, 0.f, 0.f, 0.f, 0.f, 0.f, 0.f, 0.f};
  const float4* W2v = (const float4*)W2;
#pragma unroll
  for (int f = 0; f < 4; ++f) {
    float4 wlo = W2v[(q * 4 + f) * 2];
    float4 whi = W2v[(q * 4 + f) * 2 + 1];
    p[0] = fmaf(h[f], wlo.x, p[0]); p[1] = fmaf(h[f], wlo.y, p[1]);
    p[2] = fmaf(h[f], wlo.z, p[2]); p[3] = fmaf(h[f], wlo.w, p[3]);
    p[4] = fmaf(h[f], whi.x, p[4]); p[5] = fmaf(h[f], whi.y, p[5]);
    p[6] = fmaf(h[f], whi.z, p[6]); p[7] = fmaf(h[f], whi.w, p[7]);
  }
  // reduce over q (lane bits 0,1)
#pragma unroll
  for (int m = 1; m <= 2; m <<= 1)
#pragma unroll
    for (int j = 0; j < 8; ++j)
      p[j] += __shfl_xor(p[j], m);
  // store pre-scaled by dinv[n]
  if (sub == 0)
    *(float4*)(h1w2s + n * 8) = make_float4(dn * p[0], dn * p[1], dn * p[2], dn * p[3]);
  else if (sub == 1)
    *(float4*)(h1w2s + n * 8 + 4) = make_float4(dn * p[4], dn * p[5], dn * p[6], dn * p[7]);
}

// Layer 2 fused: gather(h1w2s) + self-loop + bias + log_softmax(8).
// 4 lanes per node: q = feat half (4 feats), e = edge half.
__global__ __launch_bounds__(256) void layer2_kernel(const int* __restrict__ srt,
                                                     const int* __restrict__ row_ofs,
                                                     const int* __restrict__ deg,
                                                     const float* __restrict__ dinv,
                                                     const float* __restrict__ h1w2s,
                                                     const float* __restrict__ b2,
                                                     float* __restrict__ out) {
  int t = blockIdx.x * 256 + threadIdx.x;
  int n = t >> 2, sub = t & 3, q = sub & 1, e = sub >> 1;
  if (n >= NN) return;
  int base = row_ofs[n], cnt = deg[n];
  int half = cnt >> 1;
  int i0 = e ? half : 0;
  int i1 = e ? cnt : half;
  float4 acc = make_float4(0.f, 0.f, 0.f, 0.f);
  int s_next = (i0 < i1) ? srt[base + i0] : 0;
  for (int i = i0; i < i1; ++i) {
    int s = s_next;
    if (i + 1 < i1) s_next = srt[base + i + 1];
    acc = f4add(acc, *(const float4*)(h1w2s + s * 8 + q * 4));
  }
  // combine edge halves (xor lane bit 1)
  acc.x += __shfl_xor(acc.x, 2);
  acc.y += __shfl_xor(acc.y, 2);
  acc.z += __shfl_xor(acc.z, 2);
  acc.w += __shfl_xor(acc.w, 2);
  float dn = dinv[n];
  float4 sv = *(const float4*)(h1w2s + n * 8 + q * 4);
  float4 bv = *(const float4*)(b2 + q * 4);
  float4 v;
  v.x = fmaf(dn, acc.x + sv.x, bv.x);
  v.y = fmaf(dn, acc.y + sv.y, bv.y);
  v.z = fmaf(dn, acc.z + sv.z, bv.z);
  v.w = fmaf(dn, acc.w + sv.w, bv.w);
  float mh = fmaxf(fmaxf(v.x, v.y), fmaxf(v.z, v.w));
  float m = fmaxf(mh, __shfl_xor(mh, 1));
  float se = expf(v.x - m) + expf(v.y - m) + expf(v.z - m) + expf(v.w - m);
  float st = se + __shfl_xor(se, 1);
  float ls = m + logf(st);
  if (e == 0)
    *(float4*)(out + n * 8 + q * 4) = make_float4(v.x - ls, v.y - ls, v.z - ls, v.w - ls);
}

// ---------- launch ----------
extern "C" void kernel_launch(void* const* d_in, const int* in_sizes, int n_in,
                              void* d_out, int out_size, void* d_ws, size_t ws_size,
                              hipStream_t stream) {
  const float* x  = (const float*)d_in[0];
  const int*   ei = (const int*)d_in[1];
  const float* W1 = (const float*)d_in[2];
  const float* b1 = (const float*)d_in[3];
  const float* W2 = (const float*)d_in[4];
  const float* b2 = (const float*)d_in[5];
  float* out = (float*)d_out;

  // region0: pairs (28.8 MB) ALIASES xw1s/h1w2s (9.6 MB). Safe: pairs dead
  // after sort_kernel; floats written only after it.
  const size_t region0_bytes = (size_t)NB * CAP * sizeof(int2);
  int2*  pairs   = (int2*)d_ws;
  float* xw1s    = (float*)d_ws;                 // 16N
  float* h1w2s   = xw1s + (size_t)16 * NN;       // 8N (ends 9.6MB < region0)
  float* dinv    = (float*)((char*)d_ws + region0_bytes);  // N
  int*   deg     = (int*)(dinv + NN);            // N
  int*   row_ofs = deg + NN;                     // N
  int*   srt     = row_ofs + NN;                 // NE
  int*   bucket_cursor = srt + NE;               // NB (memset)
  int*   bucket_scan   = bucket_cursor + NB + 1; // NB
  int*   flag          = bucket_scan + NB + 1;   // 1

  hipMemsetAsync(bucket_cursor, 0, NB * sizeof(int), stream);
  detect_kernel<<<1, 64, 0, stream>>>(ei, flag);
  bin_kernel<<<(NE + CH_A - 1) / CH_A, 256, 0, stream>>>(ei, bucket_cursor, pairs, flag);
  bscan_kernel<<<1, 256, 0, stream>>>(bucket_cursor, bucket_scan);
  sort_kernel<<<NB, 256, 0, stream>>>(pairs, bucket_cursor, bucket_scan, srt, deg, row_ofs, dinv);
  gemm1_kernel<<<NN / 16, 256, 0, stream>>>(x, W1, dinv, xw1s);
  layer1_kernel<<<(8 * NN + 255) / 256, 256, 0, stream>>>(srt, row_ofs, deg, dinv, xw1s, W2, b1, h1w2s);
  layer2_kernel<<<(4 * NN + 255) / 256, 256, 0, stream>>>(srt, row_ofs, deg, dinv, h1w2s, b2, out);
}

// Round 6
// 330.791 us; speedup vs baseline: 4.8787x; 1.0200x over previous
//
#include <hip/hip_runtime.h>

#define NN 100000
#define NE 3200000
#define NB 391        // coarse buckets: dst>>8, 256 nodes each
#define CAP 9216      // per-bucket pair capacity (mean 8184, sigma~90, +11 sigma)
#define PB 16         // edges per thread in bin_kernel
#define CH_A (256 * PB)

// ---------- helpers ----------
__device__ __forceinline__ float4 f4add(float4 a, float4 b) {
  return make_float4(a.x + b.x, a.y + b.y, a.z + b.z, a.w + b.w);
}
__device__ __forceinline__ float4 f4fma(float s, float4 a, float4 c) {
  c.x = fmaf(s, a.x, c.x); c.y = fmaf(s, a.y, c.y);
  c.z = fmaf(s, a.z, c.z); c.w = fmaf(s, a.w, c.w);
  return c;
}

template<int CTRL>
__device__ __forceinline__ float4 quad_bcast(float4 v) {
  float4 r;
  r.x = __int_as_float(__builtin_amdgcn_update_dpp(__float_as_int(v.x), __float_as_int(v.x), CTRL, 0xF, 0xF, false));
  r.y = __int_as_float(__builtin_amdgcn_update_dpp(__float_as_int(v.y), __float_as_int(v.y), CTRL, 0xF, 0xF, false));
  r.z = __int_as_float(__builtin_amdgcn_update_dpp(__float_as_int(v.z), __float_as_int(v.z), CTRL, 0xF, 0xF, false));
  r.w = __int_as_float(__builtin_amdgcn_update_dpp(__float_as_int(v.w), __float_as_int(v.w), CTRL, 0xF, 0xF, false));
  return r;
}

// edge_index may be int32 or int64 (values < 2^31, nonneg -> int64 high words are 0)
__device__ __forceinline__ int edge_val(const int* __restrict__ ei, int idx, bool w64) {
  return w64 ? ei[2 * idx] : ei[idx];
}

// ---------- kernels ----------
__global__ void detect_kernel(const int* __restrict__ ei, int* __restrict__ flag) {
  if (threadIdx.x == 0 && blockIdx.x == 0) {
    int o = 0;
    for (int i = 1; i < 64; i += 2) o |= ei[i];
    *flag = (o == 0) ? 1 : 0;   // 1 => int64 layout
  }
}

// Pass A: coarse-bucket edges, coalesced PACKED writes (src|24b + dstlow|8b).
__global__ __launch_bounds__(256) void bin_kernel(const int* __restrict__ ei,
                                                  int* __restrict__ bucket_cursor,
                                                  int* __restrict__ pairs,
                                                  const int* __restrict__ flag) {
  __shared__ int  cnt[4][NB];
  __shared__ int  wcur[4][NB];   // per-wave staging cursor (block-local slot)
  __shared__ int  lbase[NB];     // block-local exclusive scan of bucket totals
  __shared__ int  gbase[NB];     // reserved base within bucket region
  __shared__ int  sc[512];
  __shared__ int2 stage[CH_A];   // 32 KB
  int t = threadIdx.x;
  int wv = t >> 6;
  for (int k = t; k < 4 * NB; k += 256) (&cnt[0][0])[k] = 0;
  __syncthreads();
  bool w64 = (*flag != 0);
  int base = blockIdx.x * CH_A;
  int nval = min(CH_A, NE - base);
  int s[PB], d[PB];
#pragma unroll
  for (int i = 0; i < PB; ++i) {
    int e = base + i * 256 + t;
    if (e < NE) {
      s[i] = edge_val(ei, e, w64);
      d[i] = edge_val(ei, NE + e, w64);
      atomicAdd(&cnt[wv][d[i] >> 8], 1);
    } else {
      d[i] = -1;
    }
  }
  __syncthreads();
  // block scan over bucket totals (512-wide, 2 per thread)
  int tA = (t < NB) ? cnt[0][t] + cnt[1][t] + cnt[2][t] + cnt[3][t] : 0;
  int tB = (t + 256 < NB) ? cnt[0][t + 256] + cnt[1][t + 256] + cnt[2][t + 256] + cnt[3][t + 256] : 0;
  sc[t] = tA; sc[t + 256] = tB;
  __syncthreads();
#pragma unroll
  for (int off = 1; off < 512; off <<= 1) {
    int u0 = (t >= off) ? sc[t - off] : 0;
    int u1 = (t + 256 >= off) ? sc[t + 256 - off] : 0;
    __syncthreads();
    sc[t] += u0; sc[t + 256] += u1;
    __syncthreads();
  }
#pragma unroll
  for (int h = 0; h < 2; ++h) {
    int k = t + h * 256;
    if (k < NB) {
      int tot = (h == 0) ? tA : tB;
      int lb = sc[k] - tot;
      lbase[k] = lb;
      gbase[k] = (tot > 0) ? atomicAdd(&bucket_cursor[k], tot) : 0;
      int c0 = cnt[0][k], c1 = cnt[1][k], c2 = cnt[2][k];
      wcur[0][k] = lb;
      wcur[1][k] = lb + c0;
      wcur[2][k] = lb + c0 + c1;
      wcur[3][k] = lb + c0 + c1 + c2;
    }
  }
  __syncthreads();
#pragma unroll
  for (int i = 0; i < PB; ++i) {
    if (d[i] >= 0) {
      int b = d[i] >> 8;
      int slot = atomicAdd(&wcur[wv][b], 1);
      stage[slot] = make_int2(s[i], d[i]);
    }
  }
  __syncthreads();
  // coalesced writeout: consecutive k are runs within one bucket; packed 4B
  for (int k = t; k < nval; k += 256) {
    int2 p = stage[k];
    int b = p.y >> 8;
    pairs[(size_t)b * CAP + gbase[b] + (k - lbase[b])] = p.x | ((p.y & 255) << 24);
  }
}

// exclusive scan of NB (<=512) bucket counts, single block of 256
__global__ __launch_bounds__(256) void bscan_kernel(const int* __restrict__ bucket_cursor,
                                                    int* __restrict__ bucket_scan) {
  __shared__ int sc[512];
  __shared__ int orig[512];
  int t = threadIdx.x;
  int v0 = (t < NB) ? bucket_cursor[t] : 0;
  int v1 = (t + 256 < NB) ? bucket_cursor[t + 256] : 0;
  sc[t] = v0; orig[t] = v0;
  sc[t + 256] = v1; orig[t + 256] = v1;
  __syncthreads();
#pragma unroll
  for (int off = 1; off < 512; off <<= 1) {
    int u0 = (t >= off) ? sc[t - off] : 0;
    int u1 = (t + 256 >= off) ? sc[t + 256 - off] : 0;
    __syncthreads();
    sc[t] += u0; sc[t + 256] += u1;
    __syncthreads();
  }
  if (t < NB) bucket_scan[t] = sc[t] - orig[t];
  if (t + 256 < NB) bucket_scan[t + 256] = sc[t + 256] - orig[t + 256];
}

// Pass B: one 512-thread block per 256-node bucket. Per-node histogram, scan
// -> deg/row_ofs/dinv, scatter src into srt within a ~32KB window.
__global__ __launch_bounds__(512) void sort_kernel(const int* __restrict__ pairs,
                                                   const int* __restrict__ bucket_cursor,
                                                   const int* __restrict__ bucket_scan,
                                                   int* __restrict__ srt,
                                                   int* __restrict__ deg,
                                                   int* __restrict__ row_ofs,
                                                   float* __restrict__ dinv) {
  __shared__ int hist[256];
  __shared__ int sc[256];
  __shared__ int cur[256];
  int t = threadIdx.x;
  int b = blockIdx.x;
  int cnt_b = bucket_cursor[b];
  size_t in_base = (size_t)b * CAP;
  int out_base = bucket_scan[b];
  if (t < 256) hist[t] = 0;
  __syncthreads();
  for (int i = t; i < cnt_b; i += 512) {
    int pk = pairs[in_base + i];
    atomicAdd(&hist[((unsigned)pk) >> 24], 1);
  }
  __syncthreads();
  if (t < 256) sc[t] = hist[t];
  __syncthreads();
#pragma unroll
  for (int off = 1; off < 256; off <<= 1) {
    int u = (t < 256 && t >= off) ? sc[t - off] : 0;
    __syncthreads();
    if (t < 256) sc[t] += u;
    __syncthreads();
  }
  if (t < 256) {
    int excl = sc[t] - hist[t];
    cur[t] = out_base + excl;
    int n = b * 256 + t;
    if (n < NN) {
      deg[n] = hist[t];
      row_ofs[n] = out_base + excl;
      dinv[n] = rsqrtf((float)hist[t] + 1.0f);  // +1 self loop
    }
  }
  __syncthreads();
  for (int i = t; i < cnt_b; i += 512) {
    int pk = pairs[in_base + i];
    int pos = atomicAdd(&cur[((unsigned)pk) >> 24], 1);
    srt[pos] = pk & 0xFFFFFF;
  }
}

// xw1s[n][16] = dinv[n] * (x[n][256] @ W1[256][16]); wave handles 8 nodes.
// Grid: NN/32 = 3125 blocks exact.
__global__ __launch_bounds__(256) void gemm1_kernel(const float* __restrict__ x,
                                                    const float* __restrict__ W1,
                                                    const float* __restrict__ dinv,
                                                    float* __restrict__ xw1s) {
  const int lane = threadIdx.x & 63;
  const int wv   = threadIdx.x >> 6;
  const int node0 = (blockIdx.x * 4 + wv) * 8;
  const int cg = lane >> 2;
  const int jl = lane & 3;
  float4 w[16];
#pragma unroll
  for (int k = 0; k < 4; ++k)
#pragma unroll
    for (int c = 0; c < 4; ++c)
      w[k * 4 + c] = *(const float4*)(W1 + (cg * 16 + k * 4 + c) * 16 + jl * 4);
  float4 xv[8];
#pragma unroll
  for (int i = 0; i < 8; ++i)
    xv[i] = *(const float4*)(x + (size_t)(node0 + i) * 256 + lane * 4);
  float4 acc[8];
#pragma unroll
  for (int i = 0; i < 8; ++i) acc[i] = make_float4(0.f, 0.f, 0.f, 0.f);
#pragma unroll
  for (int i = 0; i < 8; ++i) {
    float4 b = quad_bcast<0x00>(xv[i]);
    acc[i] = f4fma(b.x, w[0], acc[i]);  acc[i] = f4fma(b.y, w[1], acc[i]);
    acc[i] = f4fma(b.z, w[2], acc[i]);  acc[i] = f4fma(b.w, w[3], acc[i]);
  }
#pragma unroll
  for (int i = 0; i < 8; ++i) {
    float4 b = quad_bcast<0x55>(xv[i]);
    acc[i] = f4fma(b.x, w[4], acc[i]);  acc[i] = f4fma(b.y, w[5], acc[i]);
    acc[i] = f4fma(b.z, w[6], acc[i]);  acc[i] = f4fma(b.w, w[7], acc[i]);
  }
#pragma unroll
  for (int i = 0; i < 8; ++i) {
    float4 b = quad_bcast<0xAA>(xv[i]);
    acc[i] = f4fma(b.x, w[8], acc[i]);  acc[i] = f4fma(b.y, w[9], acc[i]);
    acc[i] = f4fma(b.z, w[10], acc[i]); acc[i] = f4fma(b.w, w[11], acc[i]);
  }
#pragma unroll
  for (int i = 0; i < 8; ++i) {
    float4 b = quad_bcast<0xFF>(xv[i]);
    acc[i] = f4fma(b.x, w[12], acc[i]); acc[i] = f4fma(b.y, w[13], acc[i]);
    acc[i] = f4fma(b.z, w[14], acc[i]); acc[i] = f4fma(b.w, w[15], acc[i]);
  }
#pragma unroll
  for (int m = 4; m <= 32; m <<= 1) {
#pragma unroll
    for (int i = 0; i < 8; ++i) {
      acc[i].x += __shfl_xor(acc[i].x, m);
      acc[i].y += __shfl_xor(acc[i].y, m);
      acc[i].z += __shfl_xor(acc[i].z, m);
      acc[i].w += __shfl_xor(acc[i].w, m);
    }
  }
  if (lane < 4) {
#pragma unroll
    for (int i = 0; i < 8; ++i) {
      float dn = dinv[node0 + i];
      float4 a = acc[i];
      a.x *= dn; a.y *= dn; a.z *= dn; a.w *= dn;
      *(float4*)(xw1s + (node0 + i) * 16 + lane * 4) = a;
    }
  }
}

// Layer 1 fused: gather(xw1s) + self-loop + bias + relu + @W2, pre-scaled out.
// 16 lanes per node: q = feat group (4 feats), e = edge quarter (stride 4).
__global__ __launch_bounds__(256) void layer1_kernel(const int* __restrict__ srt,
                                                     const int* __restrict__ row_ofs,
                                                     const int* __restrict__ deg,
                                                     const float* __restrict__ dinv,
                                                     const float* __restrict__ xw1s,
                                                     const float* __restrict__ W2,
                                                     const float* __restrict__ b1,
                                                     float* __restrict__ h1w2s) {
  int t = blockIdx.x * 256 + threadIdx.x;
  int n = t >> 4, sub = t & 15, q = sub & 3, e = sub >> 2;
  if (n >= NN) return;
  int base = row_ofs[n], cnt = deg[n];
  float4 acc = make_float4(0.f, 0.f, 0.f, 0.f);
  int s_next = (e < cnt) ? srt[base + e] : 0;
  for (int i = e; i < cnt; i += 4) {
    int s = s_next;
    if (i + 4 < cnt) s_next = srt[base + i + 4];
    acc = f4add(acc, *(const float4*)(xw1s + s * 16 + q * 4));
  }
  // combine edge quarters (lane bits 2,3) -> all lanes hold full sum
#pragma unroll
  for (int m = 4; m <= 8; m <<= 1) {
    acc.x += __shfl_xor(acc.x, m);
    acc.y += __shfl_xor(acc.y, m);
    acc.z += __shfl_xor(acc.z, m);
    acc.w += __shfl_xor(acc.w, m);
  }
  float dn = dinv[n];
  float4 sv = *(const float4*)(xw1s + n * 16 + q * 4);
  float4 bv = *(const float4*)(b1 + q * 4);
  float h[4];
  h[0] = fmaxf(fmaf(dn, acc.x + sv.x, bv.x), 0.f);
  h[1] = fmaxf(fmaf(dn, acc.y + sv.y, bv.y), 0.f);
  h[2] = fmaxf(fmaf(dn, acc.z + sv.z, bv.z), 0.f);
  h[3] = fmaxf(fmaf(dn, acc.w + sv.w, bv.w), 0.f);
  float p[8] = {0.f, 0.f, 0.f, 0.f, 0.f, 0.f, 0.f, 0.f};
  const float4* W2v = (const float4*)W2;
#pragma unroll
  for (int f = 0; f < 4; ++f) {
    float4 wlo = W2v[(q * 4 + f) * 2];
    float4 whi = W2v[(q * 4 + f) * 2 + 1];
    p[0] = fmaf(h[f], wlo.x, p[0]); p[1] = fmaf(h[f], wlo.y, p[1]);
    p[2] = fmaf(h[f], wlo.z, p[2]); p[3] = fmaf(h[f], wlo.w, p[3]);
    p[4] = fmaf(h[f], whi.x, p[4]); p[5] = fmaf(h[f], whi.y, p[5]);
    p[6] = fmaf(h[f], whi.z, p[6]); p[7] = fmaf(h[f], whi.w, p[7]);
  }
  // reduce over q (lane bits 0,1)
#pragma unroll
  for (int m = 1; m <= 2; m <<= 1)
#pragma unroll
    for (int j = 0; j < 8; ++j)
      p[j] += __shfl_xor(p[j], m);
  // store pre-scaled by dinv[n]
  if (sub == 0)
    *(float4*)(h1w2s + n * 8) = make_float4(dn * p[0], dn * p[1], dn * p[2], dn * p[3]);
  else if (sub == 1)
    *(float4*)(h1w2s + n * 8 + 4) = make_float4(dn * p[4], dn * p[5], dn * p[6], dn * p[7]);
}

// Layer 2 fused: gather(h1w2s) + self-loop + bias + log_softmax(8).
// 8 lanes per node: q = feat half (4 feats), e = edge quarter (stride 4).
__global__ __launch_bounds__(256) void layer2_kernel(const int* __restrict__ srt,
                                                     const int* __restrict__ row_ofs,
                                                     const int* __restrict__ deg,
                                                     const float* __restrict__ dinv,
                                                     const float* __restrict__ h1w2s,
                                                     const float* __restrict__ b2,
                                                     float* __restrict__ out) {
  int t = blockIdx.x * 256 + threadIdx.x;
  int n = t >> 3, sub = t & 7, q = sub & 1, e = sub >> 1;
  if (n >= NN) return;
  int base = row_ofs[n], cnt = deg[n];
  float4 acc = make_float4(0.f, 0.f, 0.f, 0.f);
  int s_next = (e < cnt) ? srt[base + e] : 0;
  for (int i = e; i < cnt; i += 4) {
    int s = s_next;
    if (i + 4 < cnt) s_next = srt[base + i + 4];
    acc = f4add(acc, *(const float4*)(h1w2s + s * 8 + q * 4));
  }
  // combine edge quarters (lane bits 1,2) -> all lanes hold full feat-half sum
#pragma unroll
  for (int m = 2; m <= 4; m <<= 1) {
    acc.x += __shfl_xor(acc.x, m);
    acc.y += __shfl_xor(acc.y, m);
    acc.z += __shfl_xor(acc.z, m);
    acc.w += __shfl_xor(acc.w, m);
  }
  float dn = dinv[n];
  float4 sv = *(const float4*)(h1w2s + n * 8 + q * 4);
  float4 bv = *(const float4*)(b2 + q * 4);
  float4 v;
  v.x = fmaf(dn, acc.x + sv.x, bv.x);
  v.y = fmaf(dn, acc.y + sv.y, bv.y);
  v.z = fmaf(dn, acc.z + sv.z, bv.z);
  v.w = fmaf(dn, acc.w + sv.w, bv.w);
  float mh = fmaxf(fmaxf(v.x, v.y), fmaxf(v.z, v.w));
  float m = fmaxf(mh, __shfl_xor(mh, 1));
  float se = expf(v.x - m) + expf(v.y - m) + expf(v.z - m) + expf(v.w - m);
  float st = se + __shfl_xor(se, 1);
  float ls = m + logf(st);
  if (sub < 2)
    *(float4*)(out + n * 8 + q * 4) = make_float4(v.x - ls, v.y - ls, v.z - ls, v.w - ls);
}

// ---------- launch ----------
extern "C" void kernel_launch(void* const* d_in, const int* in_sizes, int n_in,
                              void* d_out, int out_size, void* d_ws, size_t ws_size,
                              hipStream_t stream) {
  const float* x  = (const float*)d_in[0];
  const int*   ei = (const int*)d_in[1];
  const float* W1 = (const float*)d_in[2];
  const float* b1 = (const float*)d_in[3];
  const float* W2 = (const float*)d_in[4];
  const float* b2 = (const float*)d_in[5];
  float* out = (float*)d_out;

  // region0: packed pairs (14.4 MB) ALIASES xw1s/h1w2s (9.6 MB). Safe: pairs
  // dead after sort_kernel; floats written only after it.
  const size_t region0_bytes = (size_t)NB * CAP * sizeof(int);
  int*   pairs   = (int*)d_ws;
  float* xw1s    = (float*)d_ws;                 // 16N
  float* h1w2s   = xw1s + (size_t)16 * NN;       // 8N (ends 9.6MB < region0)
  float* dinv    = (float*)((char*)d_ws + region0_bytes);  // N
  int*   deg     = (int*)(dinv + NN);            // N
  int*   row_ofs = deg + NN;                     // N
  int*   srt     = row_ofs + NN;                 // NE
  int*   bucket_cursor = srt + NE;               // NB (memset)
  int*   bucket_scan   = bucket_cursor + NB + 1; // NB
  int*   flag          = bucket_scan + NB + 1;   // 1

  hipMemsetAsync(bucket_cursor, 0, NB * sizeof(int), stream);
  detect_kernel<<<1, 64, 0, stream>>>(ei, flag);
  bin_kernel<<<(NE + CH_A - 1) / CH_A, 256, 0, stream>>>(ei, bucket_cursor, pairs, flag);
  bscan_kernel<<<1, 256, 0, stream>>>(bucket_cursor, bucket_scan);
  sort_kernel<<<NB, 512, 0, stream>>>(pairs, bucket_cursor, bucket_scan, srt, deg, row_ofs, dinv);
  gemm1_kernel<<<NN / 32, 256, 0, stream>>>(x, W1, dinv, xw1s);
  layer1_kernel<<<(16 * NN + 255) / 256, 256, 0, stream>>>(srt, row_ofs, deg, dinv, xw1s, W2, b1, h1w2s);
  layer2_kernel<<<(8 * NN + 255) / 256, 256, 0, stream>>>(srt, row_ofs, deg, dinv, h1w2s, b2, out);
}